// Round 1
// baseline (1625.848 us; speedup 1.0000x reference)
//
#include <hip/hip_runtime.h>
#include <cstddef>

#define NU 50000
#define NI 25000
#define DIMN 128
#define EH 600000
#define ER 1000000

// ---------------- helpers ----------------
__device__ __forceinline__ float wave_sum64(float v) {
#pragma unroll
  for (int m = 32; m >= 1; m >>= 1) v += __shfl_xor(v, m, 64);
  return v;
}

struct Graphs {
  const int* row[5];
  const int* col[5];
  const float* val[5];
};

__device__ __forceinline__ int g_E(int z) {
  const int E[5] = {EH, EH, EH, ER, ER};
  return E[z];
}
__device__ __forceinline__ int g_n(int z) {
  const int n[5] = {NU, NU, NU, NU, NI};
  return n[z];
}
__device__ __forceinline__ int g_coff(int z) {
  const int c[5] = {0, NU, 2 * NU, 3 * NU, 4 * NU};
  return c[z];
}
__device__ __forceinline__ int g_poff(int z) { return g_coff(z) + z; }
__device__ __forceinline__ int g_eoff(int z) {
  const int e[5] = {0, EH, 2 * EH, 3 * EH, 3 * EH + ER};
  return e[z];
}

// ---------------- att_vec = attention_mat @ attention ----------------
__global__ void k_attvec(const float* __restrict__ attm, const float* __restrict__ att,
                         float* __restrict__ attv) {
  int e = threadIdx.x;  // 128 threads
  float s = 0.f;
  for (int d = 0; d < DIMN; ++d) s += attm[e * DIMN + d] * att[d];
  attv[e] = s;
}

// ---------------- gating: out = U * sigmoid(U @ W_c + b_c) ----------------
__global__ __launch_bounds__(256) void k_gate(const float* __restrict__ U,
                                              const float* __restrict__ W,
                                              const float* __restrict__ B, float* o0, float* o1,
                                              float* o2, float* o3, float* o3b, int nrows) {
  int c = blockIdx.y;
  const float* Wc = W + (size_t)c * DIMN * DIMN;
  float* out = (c == 0) ? o0 : (c == 1) ? o1 : (c == 2) ? o2 : o3;
  int row0 = blockIdx.x * 64;
  __shared__ float u_lds[64][129];
  int t = threadIdx.x, tx = t & 31, ty = t >> 5;
  for (int i = t; i < 64 * 32; i += 256) {
    int r = i >> 5, c4 = (i & 31) * 4;
    float4 v = make_float4(0.f, 0.f, 0.f, 0.f);
    if (row0 + r < nrows) v = *(const float4*)(U + (size_t)(row0 + r) * DIMN + c4);
    u_lds[r][c4] = v.x;
    u_lds[r][c4 + 1] = v.y;
    u_lds[r][c4 + 2] = v.z;
    u_lds[r][c4 + 3] = v.w;
  }
  __syncthreads();
  float acc[8][4] = {};
  for (int e = 0; e < DIMN; ++e) {
    float4 wv = *(const float4*)(Wc + (size_t)e * DIMN + tx * 4);
#pragma unroll
    for (int i = 0; i < 8; ++i) {
      float u = u_lds[ty * 8 + i][e];
      acc[i][0] += u * wv.x;
      acc[i][1] += u * wv.y;
      acc[i][2] += u * wv.z;
      acc[i][3] += u * wv.w;
    }
  }
  float4 b4 = *(const float4*)(B + c * DIMN + tx * 4);
#pragma unroll
  for (int i = 0; i < 8; ++i) {
    int r = row0 + ty * 8 + i;
    if (r >= nrows) continue;
    float ux = u_lds[ty * 8 + i][tx * 4 + 0];
    float uy = u_lds[ty * 8 + i][tx * 4 + 1];
    float uz = u_lds[ty * 8 + i][tx * 4 + 2];
    float uw = u_lds[ty * 8 + i][tx * 4 + 3];
    float4 o;
    o.x = ux / (1.f + __expf(-(acc[i][0] + b4.x)));
    o.y = uy / (1.f + __expf(-(acc[i][1] + b4.y)));
    o.z = uz / (1.f + __expf(-(acc[i][2] + b4.z)));
    o.w = uw / (1.f + __expf(-(acc[i][3] + b4.w)));
    *(float4*)(out + (size_t)r * DIMN + tx * 4) = o;
    if (c == 3) *(float4*)(o3b + (size_t)r * DIMN + tx * 4) = o;
  }
}

// ---------------- float4 copy ----------------
__global__ void k_copy4(const float* __restrict__ src, float* __restrict__ dst, int n4) {
  int i = blockIdx.x * blockDim.x + threadIdx.x;
  if (i < n4) ((float4*)dst)[i] = ((const float4*)src)[i];
}

// ---------------- CSR build ----------------
__global__ void k_hist(Graphs g, int* __restrict__ cnt) {
  int z = blockIdx.y;
  int E = g_E(z), off = g_coff(z);
  const int* __restrict__ row = g.row[z];
  for (int e = blockIdx.x * blockDim.x + threadIdx.x; e < E; e += gridDim.x * blockDim.x)
    atomicAdd(&cnt[off + row[e]], 1);
}

__global__ void k_scan1(const int* __restrict__ cnt, int* __restrict__ bsum) {
  int z = blockIdx.y, b = blockIdx.x, t = threadIdx.x;
  int n = g_n(z), off = g_coff(z);
  int idx = b * 256 + t;
  int v = (idx < n) ? cnt[off + idx] : 0;
  __shared__ int s[256];
  s[t] = v;
  __syncthreads();
  for (int o = 128; o > 0; o >>= 1) {
    if (t < o) s[t] += s[t + o];
    __syncthreads();
  }
  if (t == 0) bsum[z * 256 + b] = s[0];
}

__global__ void k_scan2(int* __restrict__ bsum, int* __restrict__ ptr) {
  int z = blockIdx.x, t = threadIdx.x;
  int n = g_n(z);
  int Bz = (n + 255) / 256;
  int v = (t < Bz) ? bsum[z * 256 + t] : 0;
  __shared__ int s[256];
  s[t] = v;
  __syncthreads();
  for (int o = 1; o < 256; o <<= 1) {
    int x = (t >= o) ? s[t - o] : 0;
    __syncthreads();
    s[t] += x;
    __syncthreads();
  }
  int excl = s[t] - v;
  if (t < Bz) bsum[z * 256 + t] = excl;
  if (t == 0) ptr[g_poff(z) + n] = g_E(z);
}

__global__ void k_scan3(const int* __restrict__ cnt, const int* __restrict__ bsum,
                        int* __restrict__ ptr, int* __restrict__ cursor) {
  int z = blockIdx.y, b = blockIdx.x, t = threadIdx.x;
  int n = g_n(z), off = g_coff(z), po = g_poff(z);
  int idx = b * 256 + t;
  int v = (idx < n) ? cnt[off + idx] : 0;
  __shared__ int s[256];
  s[t] = v;
  __syncthreads();
  for (int o = 1; o < 256; o <<= 1) {
    int x = (t >= o) ? s[t - o] : 0;
    __syncthreads();
    s[t] += x;
    __syncthreads();
  }
  int val = bsum[z * 256 + b] + s[t] - v;
  if (idx < n) {
    ptr[po + idx] = val;
    cursor[off + idx] = val;
  }
}

__global__ void k_place(Graphs g, int* __restrict__ cursor, int* __restrict__ ecol,
                        float* __restrict__ evalv) {
  int z = blockIdx.y;
  int E = g_E(z), off = g_coff(z), eo = g_eoff(z);
  const int* __restrict__ row = g.row[z];
  const int* __restrict__ col = g.col[z];
  const float* __restrict__ val = g.val[z];
  for (int e = blockIdx.x * blockDim.x + threadIdx.x; e < E; e += gridDim.x * blockDim.x) {
    int pos = atomicAdd(&cursor[off + row[e]], 1);
    ecol[eo + pos] = col[e];
    evalv[eo + pos] = val[e];
  }
}

// ---------------- SpMM (CSR gather, wave per row) + optional fused l2norm-accumulate ----
__global__ __launch_bounds__(256) void k_spmm(const int* __restrict__ ptr,
                                              const int* __restrict__ ecol,
                                              const float* __restrict__ evalv,
                                              const float* __restrict__ X, float* Y, float* ACC,
                                              int nrows) {
  int w = (blockIdx.x * 256 + threadIdx.x) >> 6;
  int lane = threadIdx.x & 63;
  if (w >= nrows) return;
  int s = ptr[w], t = ptr[w + 1];
  float ax = 0.f, ay = 0.f;
  for (int e = s; e < t; ++e) {
    int c = ecol[e];
    float v = evalv[e];
    float2 x = *(const float2*)(X + (size_t)c * DIMN + lane * 2);
    ax += v * x.x;
    ay += v * x.y;
  }
  size_t base = (size_t)w * DIMN + lane * 2;
  if (Y) *(float2*)(Y + base) = make_float2(ax, ay);
  if (ACC) {
    float ss = wave_sum64(ax * ax + ay * ay);
    float rs = rsqrtf(fmaxf(ss, 1e-12f));
    float2* a = (float2*)(ACC + base);
    float2 o = *a;
    o.x += ax * rs;
    o.y += ay * rs;
    *a = o;
  }
}

// ---------------- ACC += l2norm(X) (wave per row) ----------------
__global__ __launch_bounds__(256) void k_normacc(const float* __restrict__ X,
                                                 float* __restrict__ ACC, int nrows) {
  int w = (blockIdx.x * 256 + threadIdx.x) >> 6;
  int lane = threadIdx.x & 63;
  if (w >= nrows) return;
  size_t base = (size_t)w * DIMN + lane * 2;
  float2 x = *(const float2*)(X + base);
  float ss = wave_sum64(x.x * x.x + x.y * x.y);
  float rs = rsqrtf(fmaxf(ss, 1e-12f));
  float2* a = (float2*)(ACC + base);
  float2 o = *a;
  o.x += x.x * rs;
  o.y += x.y * rs;
  *a = o;
}

// ---------------- channel attention softmax mix: out = sum_k s_k c_k + 0.5*self ----------
__global__ __launch_bounds__(256) void k_mix(const float* __restrict__ c0,
                                             const float* __restrict__ c1,
                                             const float* __restrict__ c2,
                                             const float* __restrict__ sp,
                                             const float* __restrict__ attv, float* __restrict__ out,
                                             int nrows) {
  int w = (blockIdx.x * 256 + threadIdx.x) >> 6;
  int lane = threadIdx.x & 63;
  if (w >= nrows) return;
  size_t base = (size_t)w * DIMN + lane * 2;
  float2 x0 = *(const float2*)(c0 + base);
  float2 x1 = *(const float2*)(c1 + base);
  float2 x2 = *(const float2*)(c2 + base);
  float2 av = *(const float2*)(attv + lane * 2);
  float w0 = wave_sum64(x0.x * av.x + x0.y * av.y);
  float w1 = wave_sum64(x1.x * av.x + x1.y * av.y);
  float w2 = wave_sum64(x2.x * av.x + x2.y * av.y);
  float m = fmaxf(w0, fmaxf(w1, w2));
  float e0 = __expf(w0 - m), e1 = __expf(w1 - m), e2 = __expf(w2 - m);
  float inv = 1.f / (e0 + e1 + e2);
  float s0 = e0 * inv, s1 = e1 * inv, s2 = e2 * inv;
  float2 sv = *(const float2*)(sp + base);
  float2 o;
  o.x = s0 * x0.x + s1 * x1.x + s2 * x2.x + 0.5f * sv.x;
  o.y = s0 * x0.y + s1 * x1.y + s2 * x2.y + 0.5f * sv.y;
  *(float2*)(out + base) = o;
}

// ---------------- launch ----------------
extern "C" void kernel_launch(void* const* d_in, const int* in_sizes, int n_in, void* d_out,
                              int out_size, void* d_ws, size_t ws_size, hipStream_t stream) {
  const float* u_emb = (const float*)d_in[0];
  const float* i_emb = (const float*)d_in[1];
  const float* gW = (const float*)d_in[2];
  const float* gB = (const float*)d_in[3];
  const float* att = (const float*)d_in[4];
  const float* attm = (const float*)d_in[5];
  Graphs g;
  g.row[0] = (const int*)d_in[6];
  g.col[0] = (const int*)d_in[7];
  g.val[0] = (const float*)d_in[8];
  g.row[1] = (const int*)d_in[9];
  g.col[1] = (const int*)d_in[10];
  g.val[1] = (const float*)d_in[11];
  g.row[2] = (const int*)d_in[12];
  g.col[2] = (const int*)d_in[13];
  g.val[2] = (const float*)d_in[14];
  // R: rows = R_row (user), cols = R_col (item)
  g.row[3] = (const int*)d_in[15];
  g.col[3] = (const int*)d_in[16];
  g.val[3] = (const float*)d_in[17];
  // R^T: rows = R_col (item), cols = R_row (user)
  g.row[4] = (const int*)d_in[16];
  g.col[4] = (const int*)d_in[15];
  g.val[4] = (const float*)d_in[17];

  const size_t U = (size_t)NU * DIMN, I = (size_t)NI * DIMN;
  float* f = (float*)d_ws;
  float* G0 = f;
  float* G1 = G0 + U;
  float* G2 = G1 + U;
  float* C10 = G2 + U;
  float* C11 = C10 + U;
  float* C12 = C11 + U;
  float* MIX = C12 + U;
  float* S = MIX + U;
  float* I1 = S + U;
  float* attv = I1 + I;
  int* cnt = (int*)(attv + DIMN);
  int* ptrA = cnt + 225000;       // 4*NU + NI counts
  int* curA = ptrA + 225005;      // ptr has +1 per structure
  int* bsum = curA + 225000;
  int* ecol = bsum + 5 * 256;
  float* evalA = (float*)(ecol + (3 * EH + 2 * ER));
  float* out_u = (float*)d_out;
  float* out_i = out_u + U;

  const int TOTAL_CNT = 4 * NU + NI;  // 225000

  // ---- CSR build for all 5 structures ----
  hipMemsetAsync(cnt, 0, (size_t)TOTAL_CNT * sizeof(int), stream);
  dim3 hb(2048, 5);
  hipLaunchKernelGGL(k_hist, hb, dim3(256), 0, stream, g, cnt);
  dim3 sb(196, 5);
  hipLaunchKernelGGL(k_scan1, sb, dim3(256), 0, stream, cnt, bsum);
  hipLaunchKernelGGL(k_scan2, dim3(5), dim3(256), 0, stream, bsum, ptrA);
  hipLaunchKernelGGL(k_scan3, sb, dim3(256), 0, stream, cnt, bsum, ptrA, curA);
  hipLaunchKernelGGL(k_place, hb, dim3(256), 0, stream, g, curA, ecol, evalA);

  // ---- dense prep ----
  hipLaunchKernelGGL(k_attvec, dim3(1), dim3(128), 0, stream, attm, att, attv);
  hipLaunchKernelGGL(k_gate, dim3(782, 4), dim3(256), 0, stream, u_emb, gW, gB, G0, G1, G2, S,
                     out_u, NU);
  hipLaunchKernelGGL(k_copy4, dim3((NI * DIMN / 4 + 255) / 256), dim3(256), 0, stream, i_emb,
                     out_i, NI * DIMN / 4);

  const int poffs[5] = {0 + 0, NU + 1, 2 * NU + 2, 3 * NU + 3, 4 * NU + 4};
  const int eoffs[5] = {0, EH, 2 * EH, 3 * EH, 3 * EH + ER};
  const int GRID_U = (NU * 64 + 255) / 256;  // 12500
  const int GRID_I = (NI * 64 + 255) / 256;  // 6250

  // ---- layer 1 ----
  hipLaunchKernelGGL(k_mix, dim3(GRID_U), dim3(256), 0, stream, G0, G1, G2, S, attv, MIX, NU);
  // new_item = R^T @ mixed ; out_i += l2norm
  hipLaunchKernelGGL(k_spmm, dim3(GRID_I), dim3(256), 0, stream, ptrA + poffs[4], ecol + eoffs[4],
                     evalA + eoffs[4], MIX, I1, out_i, NI);
  // cur_s = R @ i_emb ; out_u += l2norm
  hipLaunchKernelGGL(k_spmm, dim3(GRID_U), dim3(256), 0, stream, ptrA + poffs[3], ecol + eoffs[3],
                     evalA + eoffs[3], i_emb, S, out_u, NU);
  // channel spmms (write C1k; norm-acc separately to avoid read/write race on Gk)
  hipLaunchKernelGGL(k_spmm, dim3(GRID_U), dim3(256), 0, stream, ptrA + poffs[0], ecol + eoffs[0],
                     evalA + eoffs[0], G0, C10, (float*)nullptr, NU);
  hipLaunchKernelGGL(k_spmm, dim3(GRID_U), dim3(256), 0, stream, ptrA + poffs[1], ecol + eoffs[1],
                     evalA + eoffs[1], G1, C11, (float*)nullptr, NU);
  hipLaunchKernelGGL(k_spmm, dim3(GRID_U), dim3(256), 0, stream, ptrA + poffs[2], ecol + eoffs[2],
                     evalA + eoffs[2], G2, C12, (float*)nullptr, NU);
  hipLaunchKernelGGL(k_normacc, dim3(GRID_U), dim3(256), 0, stream, C10, G0, NU);
  hipLaunchKernelGGL(k_normacc, dim3(GRID_U), dim3(256), 0, stream, C11, G1, NU);
  hipLaunchKernelGGL(k_normacc, dim3(GRID_U), dim3(256), 0, stream, C12, G2, NU);

  // ---- layer 2 ----
  hipLaunchKernelGGL(k_mix, dim3(GRID_U), dim3(256), 0, stream, C10, C11, C12, S, attv, MIX, NU);
  // item2: norm-acc only
  hipLaunchKernelGGL(k_spmm, dim3(GRID_I), dim3(256), 0, stream, ptrA + poffs[4], ecol + eoffs[4],
                     evalA + eoffs[4], MIX, (float*)nullptr, out_i, NI);
  // cur_s2 = R @ I1 : norm-acc only
  hipLaunchKernelGGL(k_spmm, dim3(GRID_U), dim3(256), 0, stream, ptrA + poffs[3], ecol + eoffs[3],
                     evalA + eoffs[3], I1, (float*)nullptr, out_u, NU);
  // channel layer-2: norm-acc into Gk (input C1k distinct -> fused is safe)
  hipLaunchKernelGGL(k_spmm, dim3(GRID_U), dim3(256), 0, stream, ptrA + poffs[0], ecol + eoffs[0],
                     evalA + eoffs[0], C10, (float*)nullptr, G0, NU);
  hipLaunchKernelGGL(k_spmm, dim3(GRID_U), dim3(256), 0, stream, ptrA + poffs[1], ecol + eoffs[1],
                     evalA + eoffs[1], C11, (float*)nullptr, G1, NU);
  hipLaunchKernelGGL(k_spmm, dim3(GRID_U), dim3(256), 0, stream, ptrA + poffs[2], ecol + eoffs[2],
                     evalA + eoffs[2], C12, (float*)nullptr, G2, NU);

  // ---- final: out_u = chan_att(fc) + 0.5*out_u (out_u currently holds sum(all_s)) ----
  hipLaunchKernelGGL(k_mix, dim3(GRID_U), dim3(256), 0, stream, G0, G1, G2, out_u, attv, out_u, NU);
}

// Round 2
// 1255.946 us; speedup vs baseline: 1.2945x; 1.2945x over previous
//
#include <hip/hip_runtime.h>
#include <cstddef>
#include <cstdint>

#define NU 50000
#define NI 25000
#define DIMN 128
#define EH 600000
#define ER 1000000

// ---------------- helpers ----------------
__device__ __forceinline__ float wave_sum64(float v) {
#pragma unroll
  for (int m = 32; m >= 1; m >>= 1) v += __shfl_xor(v, m, 64);
  return v;
}

struct Graphs {
  const int* row[5];
  const int* col[5];
  const float* val[5];
};

__device__ __forceinline__ int g_E(int z) {
  const int E[5] = {EH, EH, EH, ER, ER};
  return E[z];
}
__device__ __forceinline__ int g_n(int z) {
  const int n[5] = {NU, NU, NU, NU, NI};
  return n[z];
}
__device__ __forceinline__ int g_coff(int z) {
  const int c[5] = {0, NU, 2 * NU, 3 * NU, 4 * NU};
  return c[z];
}
__device__ __forceinline__ int g_poff(int z) { return g_coff(z) + z; }
__device__ __forceinline__ int g_eoff(int z) {
  const int e[5] = {0, EH, 2 * EH, 3 * EH, 3 * EH + ER};
  return e[z];
}

// ---------------- att_vec = attention_mat @ attention ----------------
__global__ void k_attvec(const float* __restrict__ attm, const float* __restrict__ att,
                         float* __restrict__ attv) {
  int e = threadIdx.x;  // 128 threads
  float s = 0.f;
  for (int d = 0; d < DIMN; ++d) s += attm[e * DIMN + d] * att[d];
  attv[e] = s;
}

// ---------------- gating: out = U * sigmoid(U @ W_c + b_c) ----------------
__global__ __launch_bounds__(256) void k_gate(const float* __restrict__ U,
                                              const float* __restrict__ W,
                                              const float* __restrict__ B, float* o0, float* o1,
                                              float* o2, float* o3, float* o3b, int nrows) {
  int c = blockIdx.y;
  const float* Wc = W + (size_t)c * DIMN * DIMN;
  float* out = (c == 0) ? o0 : (c == 1) ? o1 : (c == 2) ? o2 : o3;
  int row0 = blockIdx.x * 64;
  __shared__ float u_lds[64][129];
  int t = threadIdx.x, tx = t & 31, ty = t >> 5;
  for (int i = t; i < 64 * 32; i += 256) {
    int r = i >> 5, c4 = (i & 31) * 4;
    float4 v = make_float4(0.f, 0.f, 0.f, 0.f);
    if (row0 + r < nrows) v = *(const float4*)(U + (size_t)(row0 + r) * DIMN + c4);
    u_lds[r][c4] = v.x;
    u_lds[r][c4 + 1] = v.y;
    u_lds[r][c4 + 2] = v.z;
    u_lds[r][c4 + 3] = v.w;
  }
  __syncthreads();
  float acc[8][4] = {};
  for (int e = 0; e < DIMN; ++e) {
    float4 wv = *(const float4*)(Wc + (size_t)e * DIMN + tx * 4);
#pragma unroll
    for (int i = 0; i < 8; ++i) {
      float u = u_lds[ty * 8 + i][e];
      acc[i][0] += u * wv.x;
      acc[i][1] += u * wv.y;
      acc[i][2] += u * wv.z;
      acc[i][3] += u * wv.w;
    }
  }
  float4 b4 = *(const float4*)(B + c * DIMN + tx * 4);
#pragma unroll
  for (int i = 0; i < 8; ++i) {
    int r = row0 + ty * 8 + i;
    if (r >= nrows) continue;
    float ux = u_lds[ty * 8 + i][tx * 4 + 0];
    float uy = u_lds[ty * 8 + i][tx * 4 + 1];
    float uz = u_lds[ty * 8 + i][tx * 4 + 2];
    float uw = u_lds[ty * 8 + i][tx * 4 + 3];
    float4 o;
    o.x = ux / (1.f + __expf(-(acc[i][0] + b4.x)));
    o.y = uy / (1.f + __expf(-(acc[i][1] + b4.y)));
    o.z = uz / (1.f + __expf(-(acc[i][2] + b4.z)));
    o.w = uw / (1.f + __expf(-(acc[i][3] + b4.w)));
    *(float4*)(out + (size_t)r * DIMN + tx * 4) = o;
    if (c == 3) *(float4*)(o3b + (size_t)r * DIMN + tx * 4) = o;
  }
}

// ---------------- float4 copy ----------------
__global__ void k_copy4(const float* __restrict__ src, float* __restrict__ dst, int n4) {
  int i = blockIdx.x * blockDim.x + threadIdx.x;
  if (i < n4) ((float4*)dst)[i] = ((const float4*)src)[i];
}

// ---------------- CSR build ----------------
__global__ void k_hist(Graphs g, int* __restrict__ cnt) {
  int z = blockIdx.y;
  int E = g_E(z), off = g_coff(z);
  const int* __restrict__ row = g.row[z];
  for (int e = blockIdx.x * blockDim.x + threadIdx.x; e < E; e += gridDim.x * blockDim.x)
    atomicAdd(&cnt[off + row[e]], 1);
}

__global__ void k_scan1(const int* __restrict__ cnt, int* __restrict__ bsum) {
  int z = blockIdx.y, b = blockIdx.x, t = threadIdx.x;
  int n = g_n(z), off = g_coff(z);
  int idx = b * 256 + t;
  int v = (idx < n) ? cnt[off + idx] : 0;
  __shared__ int s[256];
  s[t] = v;
  __syncthreads();
  for (int o = 128; o > 0; o >>= 1) {
    if (t < o) s[t] += s[t + o];
    __syncthreads();
  }
  if (t == 0) bsum[z * 256 + b] = s[0];
}

__global__ void k_scan2(int* __restrict__ bsum, int* __restrict__ ptr) {
  int z = blockIdx.x, t = threadIdx.x;
  int n = g_n(z);
  int Bz = (n + 255) / 256;
  int v = (t < Bz) ? bsum[z * 256 + t] : 0;
  __shared__ int s[256];
  s[t] = v;
  __syncthreads();
  for (int o = 1; o < 256; o <<= 1) {
    int x = (t >= o) ? s[t - o] : 0;
    __syncthreads();
    s[t] += x;
    __syncthreads();
  }
  int excl = s[t] - v;
  if (t < Bz) bsum[z * 256 + t] = excl;
  if (t == 0) ptr[g_poff(z) + n] = g_E(z);
}

__global__ void k_scan3(const int* __restrict__ cnt, const int* __restrict__ bsum,
                        int* __restrict__ ptr, int* __restrict__ cursor) {
  int z = blockIdx.y, b = blockIdx.x, t = threadIdx.x;
  int n = g_n(z), off = g_coff(z), po = g_poff(z);
  int idx = b * 256 + t;
  int v = (idx < n) ? cnt[off + idx] : 0;
  __shared__ int s[256];
  s[t] = v;
  __syncthreads();
  for (int o = 1; o < 256; o <<= 1) {
    int x = (t >= o) ? s[t - o] : 0;
    __syncthreads();
    s[t] += x;
    __syncthreads();
  }
  int val = bsum[z * 256 + b] + s[t] - v;
  if (idx < n) {
    ptr[po + idx] = val;
    cursor[off + idx] = val;
  }
}

// packed (col, val) -> single 8B scattered store per edge (halves dirtied lines vs 2x4B)
__global__ void k_place(Graphs g, int* __restrict__ cursor, int2* __restrict__ ep) {
  int z = blockIdx.y;
  int E = g_E(z), off = g_coff(z), eo = g_eoff(z);
  const int* __restrict__ row = g.row[z];
  const int* __restrict__ col = g.col[z];
  const float* __restrict__ val = g.val[z];
  for (int e = blockIdx.x * blockDim.x + threadIdx.x; e < E; e += gridDim.x * blockDim.x) {
    int pos = atomicAdd(&cursor[off + row[e]], 1);
    ep[eo + pos] = make_int2(col[e], __float_as_int(val[e]));
  }
}

// ---------------- SpMM (CSR gather, wave per row) + optional fused l2norm-accumulate ----
__global__ __launch_bounds__(256) void k_spmm(const int* __restrict__ ptr,
                                              const int2* __restrict__ ep,
                                              const float* __restrict__ X, float* Y, float* ACC,
                                              int nrows) {
  // wave-uniform row index -> ptr/edge loads become scalar (SMEM) loads
  int w = blockIdx.x * 4 + __builtin_amdgcn_readfirstlane(threadIdx.x >> 6);
  int lane = threadIdx.x & 63;
  if (w >= nrows) return;
  int s = ptr[w], t = ptr[w + 1];
  float ax = 0.f, ay = 0.f;
  int e = s;
  for (; e + 4 <= t; e += 4) {
    int2 q0 = ep[e], q1 = ep[e + 1], q2 = ep[e + 2], q3 = ep[e + 3];
    float2 x0 = *(const float2*)(X + (size_t)q0.x * DIMN + lane * 2);
    float2 x1 = *(const float2*)(X + (size_t)q1.x * DIMN + lane * 2);
    float2 x2 = *(const float2*)(X + (size_t)q2.x * DIMN + lane * 2);
    float2 x3 = *(const float2*)(X + (size_t)q3.x * DIMN + lane * 2);
    float v0 = __int_as_float(q0.y), v1 = __int_as_float(q1.y);
    float v2 = __int_as_float(q2.y), v3 = __int_as_float(q3.y);
    ax += v0 * x0.x + v1 * x1.x + v2 * x2.x + v3 * x3.x;
    ay += v0 * x0.y + v1 * x1.y + v2 * x2.y + v3 * x3.y;
  }
  for (; e < t; ++e) {
    int2 q = ep[e];
    float2 x = *(const float2*)(X + (size_t)q.x * DIMN + lane * 2);
    float v = __int_as_float(q.y);
    ax += v * x.x;
    ay += v * x.y;
  }
  size_t base = (size_t)w * DIMN + lane * 2;
  if (Y) *(float2*)(Y + base) = make_float2(ax, ay);
  if (ACC) {
    float ss = wave_sum64(ax * ax + ay * ay);
    float rs = rsqrtf(fmaxf(ss, 1e-12f));
    float2* a = (float2*)(ACC + base);
    float2 o = *a;
    o.x += ax * rs;
    o.y += ay * rs;
    *a = o;
  }
}

// ---------------- ACC_z += l2norm(X_z) for z in {0,1,2}, one launch ----------------
__global__ __launch_bounds__(256) void k_normacc3(const float* __restrict__ X0,
                                                  const float* __restrict__ X1,
                                                  const float* __restrict__ X2, float* A0,
                                                  float* A1, float* A2, int nrows) {
  int z = blockIdx.y;
  const float* X = (z == 0) ? X0 : (z == 1) ? X1 : X2;
  float* ACC = (z == 0) ? A0 : (z == 1) ? A1 : A2;
  int w = blockIdx.x * 4 + __builtin_amdgcn_readfirstlane(threadIdx.x >> 6);
  int lane = threadIdx.x & 63;
  if (w >= nrows) return;
  size_t base = (size_t)w * DIMN + lane * 2;
  float2 x = *(const float2*)(X + base);
  float ss = wave_sum64(x.x * x.x + x.y * x.y);
  float rs = rsqrtf(fmaxf(ss, 1e-12f));
  float2* a = (float2*)(ACC + base);
  float2 o = *a;
  o.x += x.x * rs;
  o.y += x.y * rs;
  *a = o;
}

// ---------------- channel attention softmax mix: out = sum_k s_k c_k + 0.5*self ----------
__global__ __launch_bounds__(256) void k_mix(const float* __restrict__ c0,
                                             const float* __restrict__ c1,
                                             const float* __restrict__ c2,
                                             const float* __restrict__ sp,
                                             const float* __restrict__ attv, float* __restrict__ out,
                                             int nrows) {
  int w = blockIdx.x * 4 + __builtin_amdgcn_readfirstlane(threadIdx.x >> 6);
  int lane = threadIdx.x & 63;
  if (w >= nrows) return;
  size_t base = (size_t)w * DIMN + lane * 2;
  float2 x0 = *(const float2*)(c0 + base);
  float2 x1 = *(const float2*)(c1 + base);
  float2 x2 = *(const float2*)(c2 + base);
  float2 av = *(const float2*)(attv + lane * 2);
  float w0 = wave_sum64(x0.x * av.x + x0.y * av.y);
  float w1 = wave_sum64(x1.x * av.x + x1.y * av.y);
  float w2 = wave_sum64(x2.x * av.x + x2.y * av.y);
  float m = fmaxf(w0, fmaxf(w1, w2));
  float e0 = __expf(w0 - m), e1 = __expf(w1 - m), e2 = __expf(w2 - m);
  float inv = 1.f / (e0 + e1 + e2);
  float s0 = e0 * inv, s1 = e1 * inv, s2 = e2 * inv;
  float2 sv = *(const float2*)(sp + base);
  float2 o;
  o.x = s0 * x0.x + s1 * x1.x + s2 * x2.x + 0.5f * sv.x;
  o.y = s0 * x0.y + s1 * x1.y + s2 * x2.y + 0.5f * sv.y;
  *(float2*)(out + base) = o;
}

// ---------------- launch ----------------
extern "C" void kernel_launch(void* const* d_in, const int* in_sizes, int n_in, void* d_out,
                              int out_size, void* d_ws, size_t ws_size, hipStream_t stream) {
  const float* u_emb = (const float*)d_in[0];
  const float* i_emb = (const float*)d_in[1];
  const float* gW = (const float*)d_in[2];
  const float* gB = (const float*)d_in[3];
  const float* att = (const float*)d_in[4];
  const float* attm = (const float*)d_in[5];
  Graphs g;
  g.row[0] = (const int*)d_in[6];
  g.col[0] = (const int*)d_in[7];
  g.val[0] = (const float*)d_in[8];
  g.row[1] = (const int*)d_in[9];
  g.col[1] = (const int*)d_in[10];
  g.val[1] = (const float*)d_in[11];
  g.row[2] = (const int*)d_in[12];
  g.col[2] = (const int*)d_in[13];
  g.val[2] = (const float*)d_in[14];
  // R: rows = R_row (user), cols = R_col (item)
  g.row[3] = (const int*)d_in[15];
  g.col[3] = (const int*)d_in[16];
  g.val[3] = (const float*)d_in[17];
  // R^T: rows = R_col (item), cols = R_row (user)
  g.row[4] = (const int*)d_in[16];
  g.col[4] = (const int*)d_in[15];
  g.val[4] = (const float*)d_in[17];

  const size_t U = (size_t)NU * DIMN, I = (size_t)NI * DIMN;
  float* f = (float*)d_ws;
  float* G0 = f;
  float* G1 = G0 + U;
  float* G2 = G1 + U;
  float* C10 = G2 + U;
  float* C11 = C10 + U;
  float* C12 = C11 + U;
  float* MIX = C12 + U;
  float* S = MIX + U;
  float* I1 = S + U;
  float* attv = I1 + I;
  int* cnt = (int*)(attv + DIMN);
  int* ptrA = cnt + 225000;   // 4*NU + NI counts
  int* curA = ptrA + 225008;  // ptr needs 225005; padded for alignment
  int* bsum = curA + 225000;
  uintptr_t ep_addr = ((uintptr_t)(bsum + 5 * 256) + 15u) & ~(uintptr_t)15;
  int2* epack = (int2*)ep_addr;  // 3*EH + 2*ER packed (col,val) pairs
  float* out_u = (float*)d_out;
  float* out_i = out_u + U;

  const int TOTAL_CNT = 4 * NU + NI;  // 225000

  // ---- CSR build for all 5 structures ----
  hipMemsetAsync(cnt, 0, (size_t)TOTAL_CNT * sizeof(int), stream);
  dim3 hb(2048, 5);
  hipLaunchKernelGGL(k_hist, hb, dim3(256), 0, stream, g, cnt);
  dim3 sb(196, 5);
  hipLaunchKernelGGL(k_scan1, sb, dim3(256), 0, stream, cnt, bsum);
  hipLaunchKernelGGL(k_scan2, dim3(5), dim3(256), 0, stream, bsum, ptrA);
  hipLaunchKernelGGL(k_scan3, sb, dim3(256), 0, stream, cnt, bsum, ptrA, curA);
  hipLaunchKernelGGL(k_place, hb, dim3(256), 0, stream, g, curA, epack);

  // ---- dense prep ----
  hipLaunchKernelGGL(k_attvec, dim3(1), dim3(128), 0, stream, attm, att, attv);
  hipLaunchKernelGGL(k_gate, dim3(782, 4), dim3(256), 0, stream, u_emb, gW, gB, G0, G1, G2, S,
                     out_u, NU);
  hipLaunchKernelGGL(k_copy4, dim3((NI * DIMN / 4 + 255) / 256), dim3(256), 0, stream, i_emb,
                     out_i, NI * DIMN / 4);

  const int poffs[5] = {0 + 0, NU + 1, 2 * NU + 2, 3 * NU + 3, 4 * NU + 4};
  const int eoffs[5] = {0, EH, 2 * EH, 3 * EH, 3 * EH + ER};
  const int GRID_U = (NU + 3) / 4;  // 4 waves (rows) per 256-thread block
  const int GRID_I = (NI + 3) / 4;

  // ---- layer 1 ----
  hipLaunchKernelGGL(k_mix, dim3(GRID_U), dim3(256), 0, stream, G0, G1, G2, S, attv, MIX, NU);
  // new_item = R^T @ mixed ; out_i += l2norm
  hipLaunchKernelGGL(k_spmm, dim3(GRID_I), dim3(256), 0, stream, ptrA + poffs[4], epack + eoffs[4],
                     MIX, I1, out_i, NI);
  // cur_s = R @ i_emb ; out_u += l2norm
  hipLaunchKernelGGL(k_spmm, dim3(GRID_U), dim3(256), 0, stream, ptrA + poffs[3], epack + eoffs[3],
                     i_emb, S, out_u, NU);
  // channel spmms (write C1k; norm-acc separately to avoid read/write race on Gk)
  hipLaunchKernelGGL(k_spmm, dim3(GRID_U), dim3(256), 0, stream, ptrA + poffs[0], epack + eoffs[0],
                     G0, C10, (float*)nullptr, NU);
  hipLaunchKernelGGL(k_spmm, dim3(GRID_U), dim3(256), 0, stream, ptrA + poffs[1], epack + eoffs[1],
                     G1, C11, (float*)nullptr, NU);
  hipLaunchKernelGGL(k_spmm, dim3(GRID_U), dim3(256), 0, stream, ptrA + poffs[2], epack + eoffs[2],
                     G2, C12, (float*)nullptr, NU);
  hipLaunchKernelGGL(k_normacc3, dim3(GRID_U, 3), dim3(256), 0, stream, C10, C11, C12, G0, G1, G2,
                     NU);

  // ---- layer 2 ----
  hipLaunchKernelGGL(k_mix, dim3(GRID_U), dim3(256), 0, stream, C10, C11, C12, S, attv, MIX, NU);
  // item2: norm-acc only
  hipLaunchKernelGGL(k_spmm, dim3(GRID_I), dim3(256), 0, stream, ptrA + poffs[4], epack + eoffs[4],
                     MIX, (float*)nullptr, out_i, NI);
  // cur_s2 = R @ I1 : norm-acc only
  hipLaunchKernelGGL(k_spmm, dim3(GRID_U), dim3(256), 0, stream, ptrA + poffs[3], epack + eoffs[3],
                     I1, (float*)nullptr, out_u, NU);
  // channel layer-2: norm-acc into Gk (input C1k distinct -> fused is safe)
  hipLaunchKernelGGL(k_spmm, dim3(GRID_U), dim3(256), 0, stream, ptrA + poffs[0], epack + eoffs[0],
                     C10, (float*)nullptr, G0, NU);
  hipLaunchKernelGGL(k_spmm, dim3(GRID_U), dim3(256), 0, stream, ptrA + poffs[1], epack + eoffs[1],
                     C11, (float*)nullptr, G1, NU);
  hipLaunchKernelGGL(k_spmm, dim3(GRID_U), dim3(256), 0, stream, ptrA + poffs[2], epack + eoffs[2],
                     C12, (float*)nullptr, G2, NU);

  // ---- final: out_u = chan_att(fc) + 0.5*out_u (out_u currently holds sum(all_s)) ----
  hipLaunchKernelGGL(k_mix, dim3(GRID_U), dim3(256), 0, stream, G0, G1, G2, out_u, attv, out_u, NU);
}

// Round 3
// 1056.053 us; speedup vs baseline: 1.5396x; 1.1893x over previous
//
#include <hip/hip_runtime.h>
#include <cstddef>
#include <cstdint>

#define NU 50000
#define NI 25000
#define DIMN 128
#define EH 600000
#define ER 1000000

typedef unsigned int u32;

// ---------------- helpers ----------------
__device__ __forceinline__ float wave_sum64(float v) {
#pragma unroll
  for (int m = 32; m >= 1; m >>= 1) v += __shfl_xor(v, m, 64);
  return v;
}

__device__ __forceinline__ u32 pack_bf16x2(float a, float b) {
  u32 ua = __float_as_uint(a), ub = __float_as_uint(b);
  ua = (ua + 0x7fffu + ((ua >> 16) & 1u)) >> 16;
  ub = (ub + 0x7fffu + ((ub >> 16) & 1u)) >> 16;
  return ua | (ub << 16);
}
__device__ __forceinline__ float blo(u32 p) { return __uint_as_float(p << 16); }
__device__ __forceinline__ float bhi(u32 p) { return __uint_as_float(p & 0xffff0000u); }

struct Graphs {
  const int* row[5];
  const int* col[5];
  const float* val[5];
};

__device__ __forceinline__ int g_E(int z) {
  const int E[5] = {EH, EH, EH, ER, ER};
  return E[z];
}
__device__ __forceinline__ int g_n(int z) {
  const int n[5] = {NU, NU, NU, NU, NI};
  return n[z];
}
__device__ __forceinline__ int g_coff(int z) {
  const int c[5] = {0, NU, 2 * NU, 3 * NU, 4 * NU};
  return c[z];
}
__device__ __forceinline__ int g_poff(int z) { return g_coff(z) + z; }

// ---------------- att_vec = attention_mat @ attention ----------------
__global__ void k_attvec(const float* __restrict__ attm, const float* __restrict__ att,
                         float* __restrict__ attv) {
  int e = threadIdx.x;  // 128 threads
  float s = 0.f;
  for (int d = 0; d < DIMN; ++d) s += attm[e * DIMN + d] * att[d];
  attv[e] = s;
}

// ---------------- gating: out = U * sigmoid(U @ W_c + b_c), + bf16 shadow for c<3 ------
__global__ __launch_bounds__(256) void k_gate(const float* __restrict__ U,
                                              const float* __restrict__ W,
                                              const float* __restrict__ B, float* o0, float* o1,
                                              float* o2, float* o3, float* o3b, u32* s0, u32* s1,
                                              u32* s2, int nrows) {
  int c = blockIdx.y;
  const float* Wc = W + (size_t)c * DIMN * DIMN;
  float* out = (c == 0) ? o0 : (c == 1) ? o1 : (c == 2) ? o2 : o3;
  u32* sh = (c == 0) ? s0 : (c == 1) ? s1 : (c == 2) ? s2 : nullptr;
  int row0 = blockIdx.x * 64;
  __shared__ float u_lds[64][129];
  int t = threadIdx.x, tx = t & 31, ty = t >> 5;
  for (int i = t; i < 64 * 32; i += 256) {
    int r = i >> 5, c4 = (i & 31) * 4;
    float4 v = make_float4(0.f, 0.f, 0.f, 0.f);
    if (row0 + r < nrows) v = *(const float4*)(U + (size_t)(row0 + r) * DIMN + c4);
    u_lds[r][c4] = v.x;
    u_lds[r][c4 + 1] = v.y;
    u_lds[r][c4 + 2] = v.z;
    u_lds[r][c4 + 3] = v.w;
  }
  __syncthreads();
  float acc[8][4] = {};
  for (int e = 0; e < DIMN; ++e) {
    float4 wv = *(const float4*)(Wc + (size_t)e * DIMN + tx * 4);
#pragma unroll
    for (int i = 0; i < 8; ++i) {
      float u = u_lds[ty * 8 + i][e];
      acc[i][0] += u * wv.x;
      acc[i][1] += u * wv.y;
      acc[i][2] += u * wv.z;
      acc[i][3] += u * wv.w;
    }
  }
  float4 b4 = *(const float4*)(B + c * DIMN + tx * 4);
#pragma unroll
  for (int i = 0; i < 8; ++i) {
    int r = row0 + ty * 8 + i;
    if (r >= nrows) continue;
    float ux = u_lds[ty * 8 + i][tx * 4 + 0];
    float uy = u_lds[ty * 8 + i][tx * 4 + 1];
    float uz = u_lds[ty * 8 + i][tx * 4 + 2];
    float uw = u_lds[ty * 8 + i][tx * 4 + 3];
    float4 o;
    o.x = ux / (1.f + __expf(-(acc[i][0] + b4.x)));
    o.y = uy / (1.f + __expf(-(acc[i][1] + b4.y)));
    o.z = uz / (1.f + __expf(-(acc[i][2] + b4.z)));
    o.w = uw / (1.f + __expf(-(acc[i][3] + b4.w)));
    *(float4*)(out + (size_t)r * DIMN + tx * 4) = o;
    if (sh) {
      size_t sb = (size_t)r * 64 + tx * 2;
      sh[sb] = pack_bf16x2(o.x, o.y);
      sh[sb + 1] = pack_bf16x2(o.z, o.w);
    }
    if (c == 3) *(float4*)(o3b + (size_t)r * DIMN + tx * 4) = o;
  }
}

// ---------------- copy i_emb -> out_i (fp32) + IE16 bf16 shadow ----------------
__global__ void k_copy_ie(const float* __restrict__ src, float* __restrict__ dst,
                          u32* __restrict__ sh, int n2) {
  int i = blockIdx.x * blockDim.x + threadIdx.x;
  if (i >= n2) return;
  float2 v = ((const float2*)src)[i];
  ((float2*)dst)[i] = v;
  sh[i] = pack_bf16x2(v.x, v.y);
}

// ---------------- CSR build ----------------
__global__ void k_hist(Graphs g, int* __restrict__ cnt) {
  int z = blockIdx.y;
  int E = g_E(z), off = g_coff(z);
  if (blockIdx.x * 1024 >= (u32)E) return;
  const int* __restrict__ row = g.row[z];
  int e0 = blockIdx.x * 1024 + threadIdx.x;
  int r[4];
  bool ok[4];
#pragma unroll
  for (int k = 0; k < 4; ++k) {
    int e = e0 + k * 256;
    ok[k] = e < E;
    r[k] = ok[k] ? row[e] : 0;
  }
#pragma unroll
  for (int k = 0; k < 4; ++k)
    if (ok[k]) atomicAdd(&cnt[off + r[k]], 1);
}

__global__ void k_scan1(const int* __restrict__ cnt, int* __restrict__ bsum) {
  int z = blockIdx.y, b = blockIdx.x, t = threadIdx.x;
  int n = g_n(z), off = g_coff(z);
  int idx = b * 256 + t;
  int v = (idx < n) ? cnt[off + idx] : 0;
  __shared__ int s[256];
  s[t] = v;
  __syncthreads();
  for (int o = 128; o > 0; o >>= 1) {
    if (t < o) s[t] += s[t + o];
    __syncthreads();
  }
  if (t == 0) bsum[z * 256 + b] = s[0];
}

__global__ void k_scan2(int* __restrict__ bsum, int* __restrict__ ptr) {
  int z = blockIdx.x, t = threadIdx.x;
  int n = g_n(z);
  int Bz = (n + 255) / 256;
  int v = (t < Bz) ? bsum[z * 256 + t] : 0;
  __shared__ int s[256];
  s[t] = v;
  __syncthreads();
  for (int o = 1; o < 256; o <<= 1) {
    int x = (t >= o) ? s[t - o] : 0;
    __syncthreads();
    s[t] += x;
    __syncthreads();
  }
  int excl = s[t] - v;
  if (t < Bz) bsum[z * 256 + t] = excl;
  if (t == 0) ptr[g_poff(z) + n] = g_E(z);
}

__global__ void k_scan3(const int* __restrict__ cnt, const int* __restrict__ bsum,
                        int* __restrict__ ptr, int* __restrict__ cursor) {
  int z = blockIdx.y, b = blockIdx.x, t = threadIdx.x;
  int n = g_n(z), off = g_coff(z), po = g_poff(z);
  int idx = b * 256 + t;
  int v = (idx < n) ? cnt[off + idx] : 0;
  __shared__ int s[256];
  s[t] = v;
  __syncthreads();
  for (int o = 1; o < 256; o <<= 1) {
    int x = (t >= o) ? s[t - o] : 0;
    __syncthreads();
    s[t] += x;
    __syncthreads();
  }
  int val = bsum[z * 256 + b] + s[t] - v;
  if (idx < n) {
    ptr[po + idx] = val;
    cursor[off + idx] = val;
  }
}

// H structures (z<3): 8B (col,val); R structures (z>=3): 4B col only (val==1)
__global__ void k_place(Graphs g, int* __restrict__ cursor, int2* __restrict__ epH,
                        int* __restrict__ ecR) {
  int z = blockIdx.y;
  int E = g_E(z), off = g_coff(z);
  if (blockIdx.x * 1024 >= (u32)E) return;
  const int* __restrict__ row = g.row[z];
  const int* __restrict__ col = g.col[z];
  const float* __restrict__ val = g.val[z];
  int e0 = blockIdx.x * 1024 + threadIdx.x;
  int r[4], c[4], pos[4];
  float v[4];
  bool ok[4];
#pragma unroll
  for (int k = 0; k < 4; ++k) {
    int e = e0 + k * 256;
    ok[k] = e < E;
    r[k] = ok[k] ? row[e] : 0;
    c[k] = ok[k] ? col[e] : 0;
  }
  if (z < 3) {
#pragma unroll
    for (int k = 0; k < 4; ++k) {
      int e = e0 + k * 256;
      v[k] = ok[k] ? val[e] : 0.f;
    }
  }
#pragma unroll
  for (int k = 0; k < 4; ++k)
    if (ok[k]) pos[k] = atomicAdd(&cursor[off + r[k]], 1);
  if (z < 3) {
    int2* dst = epH + (size_t)z * EH;
#pragma unroll
    for (int k = 0; k < 4; ++k)
      if (ok[k]) dst[pos[k]] = make_int2(c[k], __float_as_int(v[k]));
  } else {
    int* dst = ecR + (size_t)(z - 3) * ER;
#pragma unroll
    for (int k = 0; k < 4; ++k)
      if (ok[k]) dst[pos[k]] = c[k];
  }
}

// ---------------- SpMM: CSR gather from bf16 X, fp32 accum; optional outputs ----------
template <bool UNIT>
__global__ __launch_bounds__(256) void k_spmm(const int* __restrict__ ptr,
                                              const int2* __restrict__ ep,
                                              const int* __restrict__ ecol,
                                              const u32* __restrict__ X16, float* Yf, u32* Y16,
                                              float* ACC, int nrows) {
  int w = blockIdx.x * 4 + __builtin_amdgcn_readfirstlane(threadIdx.x >> 6);
  int lane = threadIdx.x & 63;
  if (w >= nrows) return;
  int s = ptr[w], t = ptr[w + 1];
  float ax = 0.f, ay = 0.f;
  int e = s;
  for (; e + 4 <= t; e += 4) {
    int c0, c1, c2, c3;
    float v0, v1, v2, v3;
    if (UNIT) {
      c0 = ecol[e];
      c1 = ecol[e + 1];
      c2 = ecol[e + 2];
      c3 = ecol[e + 3];
    } else {
      int2 q0 = ep[e], q1 = ep[e + 1], q2 = ep[e + 2], q3 = ep[e + 3];
      c0 = q0.x;
      c1 = q1.x;
      c2 = q2.x;
      c3 = q3.x;
      v0 = __int_as_float(q0.y);
      v1 = __int_as_float(q1.y);
      v2 = __int_as_float(q2.y);
      v3 = __int_as_float(q3.y);
    }
    u32 p0 = X16[(size_t)c0 * 64 + lane];
    u32 p1 = X16[(size_t)c1 * 64 + lane];
    u32 p2 = X16[(size_t)c2 * 64 + lane];
    u32 p3 = X16[(size_t)c3 * 64 + lane];
    if (UNIT) {
      ax += blo(p0) + blo(p1) + blo(p2) + blo(p3);
      ay += bhi(p0) + bhi(p1) + bhi(p2) + bhi(p3);
    } else {
      ax += v0 * blo(p0) + v1 * blo(p1) + v2 * blo(p2) + v3 * blo(p3);
      ay += v0 * bhi(p0) + v1 * bhi(p1) + v2 * bhi(p2) + v3 * bhi(p3);
    }
  }
  for (; e < t; ++e) {
    int c;
    float v;
    if (UNIT) {
      c = ecol[e];
      v = 1.f;
    } else {
      int2 q = ep[e];
      c = q.x;
      v = __int_as_float(q.y);
    }
    u32 p = X16[(size_t)c * 64 + lane];
    ax += v * blo(p);
    ay += v * bhi(p);
  }
  size_t b64 = (size_t)w * 64 + lane;
  if (Yf) *(float2*)(Yf + 2 * b64) = make_float2(ax, ay);
  if (Y16) Y16[b64] = pack_bf16x2(ax, ay);
  if (ACC) {
    float ss = wave_sum64(ax * ax + ay * ay);
    float rs = rsqrtf(fmaxf(ss, 1e-12f));
    float2* a = (float2*)(ACC + 2 * b64);
    float2 o = *a;
    o.x += ax * rs;
    o.y += ay * rs;
    *a = o;
  }
}

// ---------------- channel attention softmax mix ----------------
template <bool SRC16, bool OUT16>
__global__ __launch_bounds__(256) void k_mix(const void* __restrict__ c0_,
                                             const void* __restrict__ c1_,
                                             const void* __restrict__ c2_,
                                             const float* __restrict__ sp,
                                             const float* __restrict__ attv, float* outf,
                                             u32* out16, int nrows) {
  int w = blockIdx.x * 4 + __builtin_amdgcn_readfirstlane(threadIdx.x >> 6);
  int lane = threadIdx.x & 63;
  if (w >= nrows) return;
  size_t b64 = (size_t)w * 64 + lane;
  float2 x0, x1, x2;
  if (SRC16) {
    u32 p0 = ((const u32*)c0_)[b64];
    u32 p1 = ((const u32*)c1_)[b64];
    u32 p2 = ((const u32*)c2_)[b64];
    x0 = make_float2(blo(p0), bhi(p0));
    x1 = make_float2(blo(p1), bhi(p1));
    x2 = make_float2(blo(p2), bhi(p2));
  } else {
    x0 = *(const float2*)((const float*)c0_ + 2 * b64);
    x1 = *(const float2*)((const float*)c1_ + 2 * b64);
    x2 = *(const float2*)((const float*)c2_ + 2 * b64);
  }
  float2 av = *(const float2*)(attv + lane * 2);
  float w0 = wave_sum64(x0.x * av.x + x0.y * av.y);
  float w1 = wave_sum64(x1.x * av.x + x1.y * av.y);
  float w2 = wave_sum64(x2.x * av.x + x2.y * av.y);
  float m = fmaxf(w0, fmaxf(w1, w2));
  float e0 = __expf(w0 - m), e1 = __expf(w1 - m), e2 = __expf(w2 - m);
  float inv = 1.f / (e0 + e1 + e2);
  float s0 = e0 * inv, s1 = e1 * inv, s2 = e2 * inv;
  float2 sv = *(const float2*)(sp + 2 * b64);
  float ox = s0 * x0.x + s1 * x1.x + s2 * x2.x + 0.5f * sv.x;
  float oy = s0 * x0.y + s1 * x1.y + s2 * x2.y + 0.5f * sv.y;
  if (OUT16)
    out16[b64] = pack_bf16x2(ox, oy);
  else
    *(float2*)(outf + 2 * b64) = make_float2(ox, oy);
}

// ---------------- launch ----------------
extern "C" void kernel_launch(void* const* d_in, const int* in_sizes, int n_in, void* d_out,
                              int out_size, void* d_ws, size_t ws_size, hipStream_t stream) {
  const float* u_emb = (const float*)d_in[0];
  const float* i_emb = (const float*)d_in[1];
  const float* gW = (const float*)d_in[2];
  const float* gB = (const float*)d_in[3];
  const float* att = (const float*)d_in[4];
  const float* attm = (const float*)d_in[5];
  Graphs g;
  g.row[0] = (const int*)d_in[6];
  g.col[0] = (const int*)d_in[7];
  g.val[0] = (const float*)d_in[8];
  g.row[1] = (const int*)d_in[9];
  g.col[1] = (const int*)d_in[10];
  g.val[1] = (const float*)d_in[11];
  g.row[2] = (const int*)d_in[12];
  g.col[2] = (const int*)d_in[13];
  g.val[2] = (const float*)d_in[14];
  g.row[3] = (const int*)d_in[15];  // R: user rows
  g.col[3] = (const int*)d_in[16];
  g.val[3] = (const float*)d_in[17];
  g.row[4] = (const int*)d_in[16];  // R^T: item rows
  g.col[4] = (const int*)d_in[15];
  g.val[4] = (const float*)d_in[17];

  const size_t U = (size_t)NU * DIMN, U64 = (size_t)NU * 64, I64 = (size_t)NI * 64;
  float* f = (float*)d_ws;
  float* G0 = f;
  float* G1 = G0 + U;
  float* G2 = G1 + U;
  float* S = G2 + U;
  u32* G016 = (u32*)(S + U);
  u32* G116 = G016 + U64;
  u32* G216 = G116 + U64;
  u32* C1016 = G216 + U64;
  u32* C1116 = C1016 + U64;
  u32* C1216 = C1116 + U64;
  u32* MIX16 = C1216 + U64;
  u32* I116 = MIX16 + U64;
  u32* IE16 = I116 + I64;
  float* attv = (float*)(IE16 + I64);
  int* cnt = (int*)(attv + DIMN);
  int* ptrA = cnt + 225000;
  int* curA = ptrA + 225008;
  int* bsum = curA + 225000;
  uintptr_t ep_addr = ((uintptr_t)(bsum + 5 * 256) + 15u) & ~(uintptr_t)15;
  int2* epH = (int2*)ep_addr;           // 3*EH packed (col,val)
  int* ecR = (int*)(epH + 3 * (size_t)EH);  // 2*ER cols
  float* out_u = (float*)d_out;
  float* out_i = out_u + U;

  const int TOTAL_CNT = 4 * NU + NI;  // 225000
  const int HB = (ER + 1023) / 1024;  // 977

  // ---- CSR build ----
  hipMemsetAsync(cnt, 0, (size_t)TOTAL_CNT * sizeof(int), stream);
  hipLaunchKernelGGL(k_hist, dim3(HB, 5), dim3(256), 0, stream, g, cnt);
  dim3 sb(196, 5);
  hipLaunchKernelGGL(k_scan1, sb, dim3(256), 0, stream, cnt, bsum);
  hipLaunchKernelGGL(k_scan2, dim3(5), dim3(256), 0, stream, bsum, ptrA);
  hipLaunchKernelGGL(k_scan3, sb, dim3(256), 0, stream, cnt, bsum, ptrA, curA);
  hipLaunchKernelGGL(k_place, dim3(HB, 5), dim3(256), 0, stream, g, curA, epH, ecR);

  // ---- dense prep ----
  hipLaunchKernelGGL(k_attvec, dim3(1), dim3(128), 0, stream, attm, att, attv);
  hipLaunchKernelGGL(k_gate, dim3(782, 4), dim3(256), 0, stream, u_emb, gW, gB, G0, G1, G2, S,
                     out_u, G016, G116, G216, NU);
  hipLaunchKernelGGL(k_copy_ie, dim3((NI * 64 + 255) / 256), dim3(256), 0, stream, i_emb, out_i,
                     IE16, NI * 64);

  const int poffs[5] = {0, NU + 1, 2 * NU + 2, 3 * NU + 3, 4 * NU + 4};
  const int GRID_U = (NU + 3) / 4;  // 4 rows (waves) per block
  const int GRID_I = (NI + 3) / 4;

  // ---- layer 1 ----
  hipLaunchKernelGGL((k_mix<false, true>), dim3(GRID_U), dim3(256), 0, stream, G0, G1, G2, S, attv,
                     (float*)nullptr, MIX16, NU);
  // new_item = R^T @ mixed ; I116 + out_i += l2norm
  hipLaunchKernelGGL((k_spmm<true>), dim3(GRID_I), dim3(256), 0, stream, ptrA + poffs[4],
                     (const int2*)nullptr, ecR + ER, MIX16, (float*)nullptr, I116, out_i, NI);
  // cur_s = R @ i_emb ; S fp32 + out_u += l2norm
  hipLaunchKernelGGL((k_spmm<true>), dim3(GRID_U), dim3(256), 0, stream, ptrA + poffs[3],
                     (const int2*)nullptr, ecR, IE16, S, (u32*)nullptr, out_u, NU);
  // channel spmms: gather Gk16 -> C1k16, fused norm-acc into Gk fp32 (distinct buffers)
  hipLaunchKernelGGL((k_spmm<false>), dim3(GRID_U), dim3(256), 0, stream, ptrA + poffs[0], epH,
                     (const int*)nullptr, G016, (float*)nullptr, C1016, G0, NU);
  hipLaunchKernelGGL((k_spmm<false>), dim3(GRID_U), dim3(256), 0, stream, ptrA + poffs[1],
                     epH + EH, (const int*)nullptr, G116, (float*)nullptr, C1116, G1, NU);
  hipLaunchKernelGGL((k_spmm<false>), dim3(GRID_U), dim3(256), 0, stream, ptrA + poffs[2],
                     epH + 2 * (size_t)EH, (const int*)nullptr, G216, (float*)nullptr, C1216, G2,
                     NU);

  // ---- layer 2 ----
  hipLaunchKernelGGL((k_mix<true, true>), dim3(GRID_U), dim3(256), 0, stream, C1016, C1116, C1216,
                     S, attv, (float*)nullptr, MIX16, NU);
  hipLaunchKernelGGL((k_spmm<true>), dim3(GRID_I), dim3(256), 0, stream, ptrA + poffs[4],
                     (const int2*)nullptr, ecR + ER, MIX16, (float*)nullptr, (u32*)nullptr, out_i,
                     NI);
  hipLaunchKernelGGL((k_spmm<true>), dim3(GRID_U), dim3(256), 0, stream, ptrA + poffs[3],
                     (const int2*)nullptr, ecR, I116, (float*)nullptr, (u32*)nullptr, out_u, NU);
  hipLaunchKernelGGL((k_spmm<false>), dim3(GRID_U), dim3(256), 0, stream, ptrA + poffs[0], epH,
                     (const int*)nullptr, C1016, (float*)nullptr, (u32*)nullptr, G0, NU);
  hipLaunchKernelGGL((k_spmm<false>), dim3(GRID_U), dim3(256), 0, stream, ptrA + poffs[1],
                     epH + EH, (const int*)nullptr, C1116, (float*)nullptr, (u32*)nullptr, G1, NU);
  hipLaunchKernelGGL((k_spmm<false>), dim3(GRID_U), dim3(256), 0, stream, ptrA + poffs[2],
                     epH + 2 * (size_t)EH, (const int*)nullptr, C1216, (float*)nullptr,
                     (u32*)nullptr, G2, NU);

  // ---- final: out_u = chan_att(fc) + 0.5*sum(all_s) ----
  hipLaunchKernelGGL((k_mix<false, false>), dim3(GRID_U), dim3(256), 0, stream, G0, G1, G2, out_u,
                     attv, out_u, (u32*)nullptr, NU);
}

// Round 4
// 1013.914 us; speedup vs baseline: 1.6035x; 1.0416x over previous
//
#include <hip/hip_runtime.h>
#include <cstddef>
#include <cstdint>

#define NU 50000
#define NI 25000
#define DIMN 128
#define EH 600000
#define ER 1000000

typedef unsigned int u32;

// ---------------- helpers ----------------
__device__ __forceinline__ float wave_sum64(float v) {
#pragma unroll
  for (int m = 32; m >= 1; m >>= 1) v += __shfl_xor(v, m, 64);
  return v;
}

__device__ __forceinline__ u32 pack_bf16x2(float a, float b) {
  u32 ua = __float_as_uint(a), ub = __float_as_uint(b);
  ua = (ua + 0x7fffu + ((ua >> 16) & 1u)) >> 16;
  ub = (ub + 0x7fffu + ((ub >> 16) & 1u)) >> 16;
  return ua | (ub << 16);
}
__device__ __forceinline__ u32 bf16_hi(float v) {  // bf16 bits of v, in high 16
  u32 u = __float_as_uint(v);
  u = (u + 0x7fffu + ((u >> 16) & 1u)) & 0xffff0000u;
  return u;
}
__device__ __forceinline__ float blo(u32 p) { return __uint_as_float(p << 16); }
__device__ __forceinline__ float bhi(u32 p) { return __uint_as_float(p & 0xffff0000u); }

struct Graphs {
  const int* row[5];
  const int* col[5];
  const float* val[5];
};

__device__ __forceinline__ int g_E(int z) {
  const int E[5] = {EH, EH, EH, ER, ER};
  return E[z];
}
__device__ __forceinline__ int g_n(int z) {
  const int n[5] = {NU, NU, NU, NU, NI};
  return n[z];
}
__device__ __forceinline__ int g_coff(int z) {
  const int c[5] = {0, NU, 2 * NU, 3 * NU, 4 * NU};
  return c[z];
}
__device__ __forceinline__ int g_poff(int z) { return g_coff(z) + z; }

// ---------------- att_vec = attention_mat @ attention ----------------
__global__ void k_attvec(const float* __restrict__ attm, const float* __restrict__ att,
                         float* __restrict__ attv) {
  int e = threadIdx.x;  // 128 threads
  float s = 0.f;
  for (int d = 0; d < DIMN; ++d) s += attm[e * DIMN + d] * att[d];
  attv[e] = s;
}

// ---------------- gating: out = U * sigmoid(U @ W_c + b_c), + bf16 shadow for c<3 ------
__global__ __launch_bounds__(256) void k_gate(const float* __restrict__ U,
                                              const float* __restrict__ W,
                                              const float* __restrict__ B, float* o0, float* o1,
                                              float* o2, float* o3, float* o3b, u32* s0, u32* s1,
                                              u32* s2, int nrows) {
  int c = blockIdx.y;
  const float* Wc = W + (size_t)c * DIMN * DIMN;
  float* out = (c == 0) ? o0 : (c == 1) ? o1 : (c == 2) ? o2 : o3;
  u32* sh = (c == 0) ? s0 : (c == 1) ? s1 : (c == 2) ? s2 : nullptr;
  int row0 = blockIdx.x * 64;
  __shared__ float u_lds[64][129];
  int t = threadIdx.x, tx = t & 31, ty = t >> 5;
  for (int i = t; i < 64 * 32; i += 256) {
    int r = i >> 5, c4 = (i & 31) * 4;
    float4 v = make_float4(0.f, 0.f, 0.f, 0.f);
    if (row0 + r < nrows) v = *(const float4*)(U + (size_t)(row0 + r) * DIMN + c4);
    u_lds[r][c4] = v.x;
    u_lds[r][c4 + 1] = v.y;
    u_lds[r][c4 + 2] = v.z;
    u_lds[r][c4 + 3] = v.w;
  }
  __syncthreads();
  float acc[8][4] = {};
  for (int e = 0; e < DIMN; ++e) {
    float4 wv = *(const float4*)(Wc + (size_t)e * DIMN + tx * 4);
#pragma unroll
    for (int i = 0; i < 8; ++i) {
      float u = u_lds[ty * 8 + i][e];
      acc[i][0] += u * wv.x;
      acc[i][1] += u * wv.y;
      acc[i][2] += u * wv.z;
      acc[i][3] += u * wv.w;
    }
  }
  float4 b4 = *(const float4*)(B + c * DIMN + tx * 4);
#pragma unroll
  for (int i = 0; i < 8; ++i) {
    int r = row0 + ty * 8 + i;
    if (r >= nrows) continue;
    float ux = u_lds[ty * 8 + i][tx * 4 + 0];
    float uy = u_lds[ty * 8 + i][tx * 4 + 1];
    float uz = u_lds[ty * 8 + i][tx * 4 + 2];
    float uw = u_lds[ty * 8 + i][tx * 4 + 3];
    float4 o;
    o.x = ux / (1.f + __expf(-(acc[i][0] + b4.x)));
    o.y = uy / (1.f + __expf(-(acc[i][1] + b4.y)));
    o.z = uz / (1.f + __expf(-(acc[i][2] + b4.z)));
    o.w = uw / (1.f + __expf(-(acc[i][3] + b4.w)));
    *(float4*)(out + (size_t)r * DIMN + tx * 4) = o;
    if (sh) {
      size_t sb = (size_t)r * 64 + tx * 2;
      sh[sb] = pack_bf16x2(o.x, o.y);
      sh[sb + 1] = pack_bf16x2(o.z, o.w);
    }
    if (c == 3) *(float4*)(o3b + (size_t)r * DIMN + tx * 4) = o;
  }
}

// ---------------- copy i_emb -> out_i (fp32) + IE16 bf16 shadow ----------------
__global__ void k_copy_ie(const float* __restrict__ src, float* __restrict__ dst,
                          u32* __restrict__ sh, int n2) {
  int i = blockIdx.x * blockDim.x + threadIdx.x;
  if (i >= n2) return;
  float2 v = ((const float2*)src)[i];
  ((float2*)dst)[i] = v;
  sh[i] = pack_bf16x2(v.x, v.y);
}

// ---------------- CSR build ----------------
#define KB 8  // edges per thread in hist/place
__global__ void k_hist(Graphs g, int* __restrict__ cnt) {
  int z = blockIdx.y;
  int E = g_E(z), off = g_coff(z);
  if (blockIdx.x * (256 * KB) >= (u32)E) return;
  const int* __restrict__ row = g.row[z];
  int e0 = blockIdx.x * (256 * KB) + threadIdx.x;
  int r[KB];
  bool ok[KB];
#pragma unroll
  for (int k = 0; k < KB; ++k) {
    int e = e0 + k * 256;
    ok[k] = e < E;
    r[k] = ok[k] ? row[e] : 0;
  }
#pragma unroll
  for (int k = 0; k < KB; ++k)
    if (ok[k]) atomicAdd(&cnt[off + r[k]], 1);
}

__global__ void k_scan1(const int* __restrict__ cnt, int* __restrict__ bsum) {
  int z = blockIdx.y, b = blockIdx.x, t = threadIdx.x;
  int n = g_n(z), off = g_coff(z);
  int idx = b * 256 + t;
  int v = (idx < n) ? cnt[off + idx] : 0;
  __shared__ int s[256];
  s[t] = v;
  __syncthreads();
  for (int o = 128; o > 0; o >>= 1) {
    if (t < o) s[t] += s[t + o];
    __syncthreads();
  }
  if (t == 0) bsum[z * 256 + b] = s[0];
}

__global__ void k_scan2(int* __restrict__ bsum, int* __restrict__ ptr) {
  int z = blockIdx.x, t = threadIdx.x;
  int n = g_n(z);
  int Bz = (n + 255) / 256;
  int v = (t < Bz) ? bsum[z * 256 + t] : 0;
  __shared__ int s[256];
  s[t] = v;
  __syncthreads();
  for (int o = 1; o < 256; o <<= 1) {
    int x = (t >= o) ? s[t - o] : 0;
    __syncthreads();
    s[t] += x;
    __syncthreads();
  }
  int excl = s[t] - v;
  if (t < Bz) bsum[z * 256 + t] = excl;
  if (t == 0) ptr[g_poff(z) + n] = g_E(z);
}

__global__ void k_scan3(const int* __restrict__ cnt, const int* __restrict__ bsum,
                        int* __restrict__ ptr, int* __restrict__ cursor) {
  int z = blockIdx.y, b = blockIdx.x, t = threadIdx.x;
  int n = g_n(z), off = g_coff(z), po = g_poff(z);
  int idx = b * 256 + t;
  int v = (idx < n) ? cnt[off + idx] : 0;
  __shared__ int s[256];
  s[t] = v;
  __syncthreads();
  for (int o = 1; o < 256; o <<= 1) {
    int x = (t >= o) ? s[t - o] : 0;
    __syncthreads();
    s[t] += x;
    __syncthreads();
  }
  int val = bsum[z * 256 + b] + s[t] - v;
  if (idx < n) {
    ptr[po + idx] = val;
    cursor[off + idx] = val;
  }
}

// H (z<3): 4B packed (bf16val<<16)|col ; R (z>=3): 4B col only (val==1)
__global__ void k_place(Graphs g, int* __restrict__ cursor, u32* __restrict__ epH,
                        int* __restrict__ ecR) {
  int z = blockIdx.y;
  int E = g_E(z), off = g_coff(z);
  if (blockIdx.x * (256 * KB) >= (u32)E) return;
  const int* __restrict__ row = g.row[z];
  const int* __restrict__ col = g.col[z];
  const float* __restrict__ val = g.val[z];
  int e0 = blockIdx.x * (256 * KB) + threadIdx.x;
  int r[KB], pos[KB];
  u32 payload[KB];
  bool ok[KB];
#pragma unroll
  for (int k = 0; k < KB; ++k) {
    int e = e0 + k * 256;
    ok[k] = e < E;
    r[k] = ok[k] ? row[e] : 0;
    payload[k] = ok[k] ? (u32)col[e] : 0u;
  }
  if (z < 3) {
#pragma unroll
    for (int k = 0; k < KB; ++k) {
      int e = e0 + k * 256;
      payload[k] |= ok[k] ? bf16_hi(val[e]) : 0u;
    }
  }
#pragma unroll
  for (int k = 0; k < KB; ++k)
    if (ok[k]) pos[k] = atomicAdd(&cursor[off + r[k]], 1);
  if (z < 3) {
    u32* dst = epH + (size_t)z * EH;
#pragma unroll
    for (int k = 0; k < KB; ++k)
      if (ok[k]) dst[pos[k]] = payload[k];
  } else {
    int* dst = ecR + (size_t)(z - 3) * ER;
#pragma unroll
    for (int k = 0; k < KB; ++k)
      if (ok[k]) dst[pos[k]] = (int)payload[k];
  }
}

// ---------------- SpMM: CSR gather from bf16 X, fp32 accum; optional outputs ----------
template <bool UNIT>
__global__ __launch_bounds__(256) void k_spmm(const int* __restrict__ ptr,
                                              const u32* __restrict__ ep,
                                              const int* __restrict__ ecol,
                                              const u32* __restrict__ X16, float* Yf, u32* Y16,
                                              float* ACC, int nrows) {
  int w = blockIdx.x * 4 + __builtin_amdgcn_readfirstlane(threadIdx.x >> 6);
  int lane = threadIdx.x & 63;
  if (w >= nrows) return;
  int s = ptr[w], t = ptr[w + 1];
  float ax = 0.f, ay = 0.f;
  int e = s;
  for (; e + 8 <= t; e += 8) {
    int cc[8];
    float vv[8];
#pragma unroll
    for (int k = 0; k < 8; ++k) {
      if (UNIT) {
        cc[k] = ecol[e + k];
      } else {
        u32 q = ep[e + k];
        cc[k] = (int)(q & 0xffffu);
        vv[k] = bhi(q);
      }
    }
    u32 p[8];
#pragma unroll
    for (int k = 0; k < 8; ++k) p[k] = X16[(size_t)cc[k] * 64 + lane];
#pragma unroll
    for (int k = 0; k < 8; ++k) {
      if (UNIT) {
        ax += blo(p[k]);
        ay += bhi(p[k]);
      } else {
        ax += vv[k] * blo(p[k]);
        ay += vv[k] * bhi(p[k]);
      }
    }
  }
  for (; e + 4 <= t; e += 4) {
    int cc[4];
    float vv[4];
#pragma unroll
    for (int k = 0; k < 4; ++k) {
      if (UNIT) {
        cc[k] = ecol[e + k];
      } else {
        u32 q = ep[e + k];
        cc[k] = (int)(q & 0xffffu);
        vv[k] = bhi(q);
      }
    }
    u32 p[4];
#pragma unroll
    for (int k = 0; k < 4; ++k) p[k] = X16[(size_t)cc[k] * 64 + lane];
#pragma unroll
    for (int k = 0; k < 4; ++k) {
      if (UNIT) {
        ax += blo(p[k]);
        ay += bhi(p[k]);
      } else {
        ax += vv[k] * blo(p[k]);
        ay += vv[k] * bhi(p[k]);
      }
    }
  }
  for (; e < t; ++e) {
    int c;
    float v = 1.f;
    if (UNIT) {
      c = ecol[e];
    } else {
      u32 q = ep[e];
      c = (int)(q & 0xffffu);
      v = bhi(q);
    }
    u32 p = X16[(size_t)c * 64 + lane];
    ax += v * blo(p);
    ay += v * bhi(p);
  }
  size_t b64 = (size_t)w * 64 + lane;
  if (Yf) *(float2*)(Yf + 2 * b64) = make_float2(ax, ay);
  if (Y16) Y16[b64] = pack_bf16x2(ax, ay);
  if (ACC) {
    float ss = wave_sum64(ax * ax + ay * ay);
    float rs = rsqrtf(fmaxf(ss, 1e-12f));
    float2* a = (float2*)(ACC + 2 * b64);
    float2 o = *a;
    o.x += ax * rs;
    o.y += ay * rs;
    *a = o;
  }
}

// ---------------- channel attention softmax mix ----------------
template <bool SRC16, bool OUT16>
__global__ __launch_bounds__(256) void k_mix(const void* __restrict__ c0_,
                                             const void* __restrict__ c1_,
                                             const void* __restrict__ c2_,
                                             const float* __restrict__ sp,
                                             const float* __restrict__ attv, float* outf,
                                             u32* out16, int nrows) {
  int w = blockIdx.x * 4 + __builtin_amdgcn_readfirstlane(threadIdx.x >> 6);
  int lane = threadIdx.x & 63;
  if (w >= nrows) return;
  size_t b64 = (size_t)w * 64 + lane;
  float2 x0, x1, x2;
  if (SRC16) {
    u32 p0 = ((const u32*)c0_)[b64];
    u32 p1 = ((const u32*)c1_)[b64];
    u32 p2 = ((const u32*)c2_)[b64];
    x0 = make_float2(blo(p0), bhi(p0));
    x1 = make_float2(blo(p1), bhi(p1));
    x2 = make_float2(blo(p2), bhi(p2));
  } else {
    x0 = *(const float2*)((const float*)c0_ + 2 * b64);
    x1 = *(const float2*)((const float*)c1_ + 2 * b64);
    x2 = *(const float2*)((const float*)c2_ + 2 * b64);
  }
  float2 av = *(const float2*)(attv + lane * 2);
  float w0 = wave_sum64(x0.x * av.x + x0.y * av.y);
  float w1 = wave_sum64(x1.x * av.x + x1.y * av.y);
  float w2 = wave_sum64(x2.x * av.x + x2.y * av.y);
  float m = fmaxf(w0, fmaxf(w1, w2));
  float e0 = __expf(w0 - m), e1 = __expf(w1 - m), e2 = __expf(w2 - m);
  float inv = 1.f / (e0 + e1 + e2);
  float s0 = e0 * inv, s1 = e1 * inv, s2 = e2 * inv;
  float2 sv = *(const float2*)(sp + 2 * b64);
  float ox = s0 * x0.x + s1 * x1.x + s2 * x2.x + 0.5f * sv.x;
  float oy = s0 * x0.y + s1 * x1.y + s2 * x2.y + 0.5f * sv.y;
  if (OUT16)
    out16[b64] = pack_bf16x2(ox, oy);
  else
    *(float2*)(outf + 2 * b64) = make_float2(ox, oy);
}

// ---------------- launch ----------------
extern "C" void kernel_launch(void* const* d_in, const int* in_sizes, int n_in, void* d_out,
                              int out_size, void* d_ws, size_t ws_size, hipStream_t stream) {
  const float* u_emb = (const float*)d_in[0];
  const float* i_emb = (const float*)d_in[1];
  const float* gW = (const float*)d_in[2];
  const float* gB = (const float*)d_in[3];
  const float* att = (const float*)d_in[4];
  const float* attm = (const float*)d_in[5];
  Graphs g;
  g.row[0] = (const int*)d_in[6];
  g.col[0] = (const int*)d_in[7];
  g.val[0] = (const float*)d_in[8];
  g.row[1] = (const int*)d_in[9];
  g.col[1] = (const int*)d_in[10];
  g.val[1] = (const float*)d_in[11];
  g.row[2] = (const int*)d_in[12];
  g.col[2] = (const int*)d_in[13];
  g.val[2] = (const float*)d_in[14];
  g.row[3] = (const int*)d_in[15];  // R: user rows
  g.col[3] = (const int*)d_in[16];
  g.val[3] = (const float*)d_in[17];
  g.row[4] = (const int*)d_in[16];  // R^T: item rows
  g.col[4] = (const int*)d_in[15];
  g.val[4] = (const float*)d_in[17];

  const size_t U = (size_t)NU * DIMN, U64 = (size_t)NU * 64, I64 = (size_t)NI * 64;
  float* f = (float*)d_ws;
  float* G0 = f;
  float* G1 = G0 + U;
  float* G2 = G1 + U;
  float* S = G2 + U;
  u32* G016 = (u32*)(S + U);
  u32* G116 = G016 + U64;
  u32* G216 = G116 + U64;
  u32* C1016 = G216 + U64;
  u32* C1116 = C1016 + U64;
  u32* C1216 = C1116 + U64;
  u32* MIX16 = C1216 + U64;
  u32* I116 = MIX16 + U64;
  u32* IE16 = I116 + I64;
  float* attv = (float*)(IE16 + I64);
  int* cnt = (int*)(attv + DIMN);
  int* ptrA = cnt + 225000;
  int* curA = ptrA + 225008;
  int* bsum = curA + 225000;
  uintptr_t ep_addr = ((uintptr_t)(bsum + 5 * 256) + 15u) & ~(uintptr_t)15;
  u32* epH = (u32*)ep_addr;                 // 3*EH packed (bf16val<<16 | col)
  int* ecR = (int*)(epH + 3 * (size_t)EH);  // 2*ER cols
  float* out_u = (float*)d_out;
  float* out_i = out_u + U;

  const int TOTAL_CNT = 4 * NU + NI;  // 225000
  const int HB = (ER + 256 * KB - 1) / (256 * KB);

  // ---- CSR build ----
  hipMemsetAsync(cnt, 0, (size_t)TOTAL_CNT * sizeof(int), stream);
  hipLaunchKernelGGL(k_hist, dim3(HB, 5), dim3(256), 0, stream, g, cnt);
  dim3 sb(196, 5);
  hipLaunchKernelGGL(k_scan1, sb, dim3(256), 0, stream, cnt, bsum);
  hipLaunchKernelGGL(k_scan2, dim3(5), dim3(256), 0, stream, bsum, ptrA);
  hipLaunchKernelGGL(k_scan3, sb, dim3(256), 0, stream, cnt, bsum, ptrA, curA);
  hipLaunchKernelGGL(k_place, dim3(HB, 5), dim3(256), 0, stream, g, curA, epH, ecR);

  // ---- dense prep ----
  hipLaunchKernelGGL(k_attvec, dim3(1), dim3(128), 0, stream, attm, att, attv);
  hipLaunchKernelGGL(k_gate, dim3(782, 4), dim3(256), 0, stream, u_emb, gW, gB, G0, G1, G2, S,
                     out_u, G016, G116, G216, NU);
  hipLaunchKernelGGL(k_copy_ie, dim3((NI * 64 + 255) / 256), dim3(256), 0, stream, i_emb, out_i,
                     IE16, NI * 64);

  const int poffs[5] = {0, NU + 1, 2 * NU + 2, 3 * NU + 3, 4 * NU + 4};
  const int GRID_U = (NU + 3) / 4;  // 4 rows (waves) per block
  const int GRID_I = (NI + 3) / 4;

  // ---- layer 1 ----
  hipLaunchKernelGGL((k_mix<false, true>), dim3(GRID_U), dim3(256), 0, stream, G0, G1, G2, S, attv,
                     (float*)nullptr, MIX16, NU);
  // new_item = R^T @ mixed ; I116 + out_i += l2norm
  hipLaunchKernelGGL((k_spmm<true>), dim3(GRID_I), dim3(256), 0, stream, ptrA + poffs[4],
                     (const u32*)nullptr, ecR + ER, MIX16, (float*)nullptr, I116, out_i, NI);
  // cur_s = R @ i_emb ; S fp32 + out_u += l2norm
  hipLaunchKernelGGL((k_spmm<true>), dim3(GRID_U), dim3(256), 0, stream, ptrA + poffs[3],
                     (const u32*)nullptr, ecR, IE16, S, (u32*)nullptr, out_u, NU);
  // channel spmms: gather Gk16 -> C1k16, fused norm-acc into Gk fp32 (distinct buffers)
  hipLaunchKernelGGL((k_spmm<false>), dim3(GRID_U), dim3(256), 0, stream, ptrA + poffs[0], epH,
                     (const int*)nullptr, G016, (float*)nullptr, C1016, G0, NU);
  hipLaunchKernelGGL((k_spmm<false>), dim3(GRID_U), dim3(256), 0, stream, ptrA + poffs[1],
                     epH + EH, (const int*)nullptr, G116, (float*)nullptr, C1116, G1, NU);
  hipLaunchKernelGGL((k_spmm<false>), dim3(GRID_U), dim3(256), 0, stream, ptrA + poffs[2],
                     epH + 2 * (size_t)EH, (const int*)nullptr, G216, (float*)nullptr, C1216, G2,
                     NU);

  // ---- layer 2 ----
  hipLaunchKernelGGL((k_mix<true, true>), dim3(GRID_U), dim3(256), 0, stream, C1016, C1116, C1216,
                     S, attv, (float*)nullptr, MIX16, NU);
  hipLaunchKernelGGL((k_spmm<true>), dim3(GRID_I), dim3(256), 0, stream, ptrA + poffs[4],
                     (const u32*)nullptr, ecR + ER, MIX16, (float*)nullptr, (u32*)nullptr, out_i,
                     NI);
  hipLaunchKernelGGL((k_spmm<true>), dim3(GRID_U), dim3(256), 0, stream, ptrA + poffs[3],
                     (const u32*)nullptr, ecR, I116, (float*)nullptr, (u32*)nullptr, out_u, NU);
  hipLaunchKernelGGL((k_spmm<false>), dim3(GRID_U), dim3(256), 0, stream, ptrA + poffs[0], epH,
                     (const int*)nullptr, C1016, (float*)nullptr, (u32*)nullptr, G0, NU);
  hipLaunchKernelGGL((k_spmm<false>), dim3(GRID_U), dim3(256), 0, stream, ptrA + poffs[1],
                     epH + EH, (const int*)nullptr, C1116, (float*)nullptr, (u32*)nullptr, G1, NU);
  hipLaunchKernelGGL((k_spmm<false>), dim3(GRID_U), dim3(256), 0, stream, ptrA + poffs[2],
                     epH + 2 * (size_t)EH, (const int*)nullptr, C1216, (float*)nullptr,
                     (u32*)nullptr, G2, NU);

  // ---- final: out_u = chan_att(fc) + 0.5*sum(all_s) ----
  hipLaunchKernelGGL((k_mix<false, false>), dim3(GRID_U), dim3(256), 0, stream, G0, G1, G2, out_u,
                     attv, out_u, (u32*)nullptr, NU);
}

// Round 5
// 688.155 us; speedup vs baseline: 2.3626x; 1.4734x over previous
//
#include <hip/hip_runtime.h>
#include <cstddef>
#include <cstdint>

#define NU 50000
#define NI 25000
#define DIMN 128
#define EH 600000
#define ER 1000000

typedef unsigned int u32;
typedef unsigned long long u64;

// ---------------- helpers ----------------
__device__ __forceinline__ float wave_sum64(float v) {
#pragma unroll
  for (int m = 32; m >= 1; m >>= 1) v += __shfl_xor(v, m, 64);
  return v;
}

__device__ __forceinline__ u32 pack_bf16x2(float a, float b) {
  u32 ua = __float_as_uint(a), ub = __float_as_uint(b);
  ua = (ua + 0x7fffu + ((ua >> 16) & 1u)) >> 16;
  ub = (ub + 0x7fffu + ((ub >> 16) & 1u)) >> 16;
  return ua | (ub << 16);
}
__device__ __forceinline__ u32 bf16_hi(float v) {  // bf16 bits of v, in high 16
  u32 u = __float_as_uint(v);
  u = (u + 0x7fffu + ((u >> 16) & 1u)) & 0xffff0000u;
  return u;
}
__device__ __forceinline__ float blo(u32 p) { return __uint_as_float(p << 16); }
__device__ __forceinline__ float bhi(u32 p) { return __uint_as_float(p & 0xffff0000u); }

struct Graphs {
  const int* row[5];
  const int* col[5];
  const float* val[5];
};

__device__ __forceinline__ int g_E(int z) {
  const int E[5] = {EH, EH, EH, ER, ER};
  return E[z];
}

// ---------------- att_vec = attention_mat @ attention ----------------
__global__ void k_attvec(const float* __restrict__ attm, const float* __restrict__ att,
                         float* __restrict__ attv) {
  int e = threadIdx.x;  // 128 threads
  float s = 0.f;
  for (int d = 0; d < DIMN; ++d) s += attm[e * DIMN + d] * att[d];
  attv[e] = s;
}

// ---------------- gating: out = U * sigmoid(U @ W_c + b_c), + bf16 shadow for c<3 ------
__global__ __launch_bounds__(256) void k_gate(const float* __restrict__ U,
                                              const float* __restrict__ W,
                                              const float* __restrict__ B, float* o0, float* o1,
                                              float* o2, float* o3, float* o3b, u32* s0, u32* s1,
                                              u32* s2, int nrows) {
  int c = blockIdx.y;
  const float* Wc = W + (size_t)c * DIMN * DIMN;
  float* out = (c == 0) ? o0 : (c == 1) ? o1 : (c == 2) ? o2 : o3;
  u32* sh = (c == 0) ? s0 : (c == 1) ? s1 : (c == 2) ? s2 : nullptr;
  int row0 = blockIdx.x * 64;
  __shared__ float u_lds[64][129];
  int t = threadIdx.x, tx = t & 31, ty = t >> 5;
  for (int i = t; i < 64 * 32; i += 256) {
    int r = i >> 5, c4 = (i & 31) * 4;
    float4 v = make_float4(0.f, 0.f, 0.f, 0.f);
    if (row0 + r < nrows) v = *(const float4*)(U + (size_t)(row0 + r) * DIMN + c4);
    u_lds[r][c4] = v.x;
    u_lds[r][c4 + 1] = v.y;
    u_lds[r][c4 + 2] = v.z;
    u_lds[r][c4 + 3] = v.w;
  }
  __syncthreads();
  float acc[8][4] = {};
  for (int e = 0; e < DIMN; ++e) {
    float4 wv = *(const float4*)(Wc + (size_t)e * DIMN + tx * 4);
#pragma unroll
    for (int i = 0; i < 8; ++i) {
      float u = u_lds[ty * 8 + i][e];
      acc[i][0] += u * wv.x;
      acc[i][1] += u * wv.y;
      acc[i][2] += u * wv.z;
      acc[i][3] += u * wv.w;
    }
  }
  float4 b4 = *(const float4*)(B + c * DIMN + tx * 4);
#pragma unroll
  for (int i = 0; i < 8; ++i) {
    int r = row0 + ty * 8 + i;
    if (r >= nrows) continue;
    float ux = u_lds[ty * 8 + i][tx * 4 + 0];
    float uy = u_lds[ty * 8 + i][tx * 4 + 1];
    float uz = u_lds[ty * 8 + i][tx * 4 + 2];
    float uw = u_lds[ty * 8 + i][tx * 4 + 3];
    float4 o;
    o.x = ux / (1.f + __expf(-(acc[i][0] + b4.x)));
    o.y = uy / (1.f + __expf(-(acc[i][1] + b4.y)));
    o.z = uz / (1.f + __expf(-(acc[i][2] + b4.z)));
    o.w = uw / (1.f + __expf(-(acc[i][3] + b4.w)));
    *(float4*)(out + (size_t)r * DIMN + tx * 4) = o;
    if (sh) {
      size_t sb = (size_t)r * 64 + tx * 2;
      sh[sb] = pack_bf16x2(o.x, o.y);
      sh[sb + 1] = pack_bf16x2(o.z, o.w);
    }
    if (c == 3) *(float4*)(o3b + (size_t)r * DIMN + tx * 4) = o;
  }
}

// ---------------- copy i_emb -> out_i (fp32) + IE16 bf16 shadow ----------------
__global__ void k_copy_ie(const float* __restrict__ src, float* __restrict__ dst,
                          u32* __restrict__ sh, int n2) {
  int i = blockIdx.x * blockDim.x + threadIdx.x;
  if (i >= n2) return;
  float2 v = ((const float2*)src)[i];
  ((float2*)dst)[i] = v;
  sh[i] = pack_bf16x2(v.x, v.y);
}

// ================= bucketed CSR build =================
// buckets: z<4 -> 256 rows/bucket (shift 8), z==4 -> 128 rows/bucket (shift 7)
// NBK buckets per structure (196 for all five).
#define NBK 196
#define CHUNK 2048  // edges per workgroup in bcount/bscat (256 thr x 8)
#define FCAP 8192   // LDS payload capacity in k_fine

__global__ __launch_bounds__(256) void k_bcount(Graphs g, int* __restrict__ bcnt) {
  int z = blockIdx.y;
  int E = g_E(z);
  if ((int)(blockIdx.x * CHUNK) >= E) return;
  int sh = (z == 4) ? 7 : 8;
  __shared__ int hist[NBK];
  for (int i = threadIdx.x; i < NBK; i += 256) hist[i] = 0;
  __syncthreads();
  const int* __restrict__ row = g.row[z];
  int e0 = blockIdx.x * CHUNK + threadIdx.x;
#pragma unroll
  for (int k = 0; k < 8; ++k) {
    int e = e0 + k * 256;
    if (e < E) atomicAdd(&hist[row[e] >> sh], 1);
  }
  __syncthreads();
  for (int i = threadIdx.x; i < NBK; i += 256)
    if (hist[i]) atomicAdd(&bcnt[z * NBK + i], hist[i]);
}

__global__ void k_bscan(const int* __restrict__ bcnt, int* __restrict__ base,
                        int* __restrict__ cur, int* __restrict__ ptr) {
  __shared__ int s[256];
  __shared__ int carry_s;
  int t = threadIdx.x;
  if (t == 0) carry_s = 0;
  __syncthreads();
  const int TOT = 5 * NBK;  // 980
  for (int c0 = 0; c0 < TOT; c0 += 256) {
    int idx = c0 + t;
    int v = (idx < TOT) ? bcnt[idx] : 0;
    s[t] = v;
    __syncthreads();
    for (int o = 1; o < 256; o <<= 1) {
      int x = (t >= o) ? s[t - o] : 0;
      __syncthreads();
      s[t] += x;
      __syncthreads();
    }
    int excl = carry_s + s[t] - v;
    if (idx < TOT) {
      base[idx] = excl;
      cur[idx] = excl;
    }
    __syncthreads();
    if (t == 0) carry_s += s[255];
    __syncthreads();
  }
  if (t == 0) base[TOT] = 3 * EH + 2 * ER;
  if (t < 5) {
    const int poffs[5] = {0, NU + 1, 2 * NU + 2, 3 * NU + 3, 4 * NU + 4};
    const int nz[5] = {NU, NU, NU, NU, NI};
    const int Ez[5] = {EH, EH, EH, ER, ER};
    ptr[poffs[t] + nz[t]] = Ez[t];
  }
}

// scatter edges into bucket regions; per-WG contiguous runs per bucket
__global__ __launch_bounds__(256) void k_bscat(Graphs g, int* __restrict__ cur,
                                               u64* __restrict__ ebkt) {
  int z = blockIdx.y;
  int E = g_E(z);
  if ((int)(blockIdx.x * CHUNK) >= E) return;
  int sh = (z == 4) ? 7 : 8;
  __shared__ int hist[NBK], basel[NBK], curl[NBK];
  for (int i = threadIdx.x; i < NBK; i += 256) {
    hist[i] = 0;
    curl[i] = 0;
  }
  __syncthreads();
  const int* __restrict__ row = g.row[z];
  const int* __restrict__ col = g.col[z];
  const float* __restrict__ val = g.val[z];
  int e0 = blockIdx.x * CHUNK + threadIdx.x;
  int r[8];
  u32 pay[8];
  bool ok[8];
#pragma unroll
  for (int k = 0; k < 8; ++k) {
    int e = e0 + k * 256;
    ok[k] = e < E;
    r[k] = ok[k] ? row[e] : 0;
    pay[k] = ok[k] ? (u32)col[e] : 0u;
  }
  if (z < 3) {
#pragma unroll
    for (int k = 0; k < 8; ++k) {
      int e = e0 + k * 256;
      if (ok[k]) pay[k] |= bf16_hi(val[e]);
    }
  }
#pragma unroll
  for (int k = 0; k < 8; ++k)
    if (ok[k]) atomicAdd(&hist[r[k] >> sh], 1);
  __syncthreads();
  for (int i = threadIdx.x; i < NBK; i += 256)
    if (hist[i]) basel[i] = atomicAdd(&cur[z * NBK + i], hist[i]);
  __syncthreads();
#pragma unroll
  for (int k = 0; k < 8; ++k)
    if (ok[k]) {
      int b = r[k] >> sh;
      int rank = atomicAdd(&curl[b], 1);
      ebkt[(size_t)(basel[b] + rank)] = ((u64)(u32)r[k] << 32) | pay[k];
    }
}

// fine placement within one bucket: LDS scatter, coalesced stream-out; writes ptr
__global__ __launch_bounds__(256) void k_fine(const u64* __restrict__ ebkt,
                                              const int* __restrict__ base,
                                              u32* __restrict__ epay, int* __restrict__ ptr) {
  int z = blockIdx.y, b = blockIdx.x, t = threadIdx.x;
  int sh = (z == 4) ? 7 : 8;
  int mask = (1 << sh) - 1;
  const int poffs[5] = {0, NU + 1, 2 * NU + 2, 3 * NU + 3, 4 * NU + 4};
  const int eoffs[5] = {0, EH, 2 * EH, 3 * EH, 3 * EH + ER};
  const int nz[5] = {NU, NU, NU, NU, NI};
  int gidx = z * NBK + b;
  int s = base[gidx], e = base[gidx + 1];
  int n = e - s;
  __shared__ int cnt[256], scn[256], curl[256];
  __shared__ u32 buf[FCAP];
  cnt[t] = 0;
  curl[t] = 0;
  __syncthreads();
  for (int i = t; i < n; i += 256) {
    int row = (int)(ebkt[s + i] >> 32);
    atomicAdd(&cnt[row & mask], 1);
  }
  __syncthreads();
  int v = cnt[t];
  scn[t] = v;
  __syncthreads();
  for (int o = 1; o < 256; o <<= 1) {
    int x = (t >= o) ? scn[t - o] : 0;
    __syncthreads();
    scn[t] += x;
    __syncthreads();
  }
  int excl = scn[t] - v;
  __syncthreads();
  scn[t] = excl;
  int rg = (b << sh) + t;
  if (t <= mask && rg < nz[z]) ptr[poffs[z] + rg] = (s - eoffs[z]) + excl;
  __syncthreads();
  if (n <= FCAP) {
    for (int i = t; i < n; i += 256) {
      u64 q = ebkt[s + i];
      int r = ((int)(q >> 32)) & mask;
      int rank = atomicAdd(&curl[r], 1);
      buf[scn[r] + rank] = (u32)q;
    }
    __syncthreads();
    for (int i = t; i < n; i += 256) epay[s + i] = buf[i];
  } else {  // overflow fallback (statistically never at these sizes)
    for (int i = t; i < n; i += 256) {
      u64 q = ebkt[s + i];
      int r = ((int)(q >> 32)) & mask;
      int rank = atomicAdd(&curl[r], 1);
      epay[s + scn[r] + rank] = (u32)q;
    }
  }
}

// ---------------- SpMM: CSR gather from bf16 X, fp32 accum; optional outputs ----------
template <bool UNIT>
__global__ __launch_bounds__(256) void k_spmm(const int* __restrict__ ptr,
                                              const u32* __restrict__ ep,
                                              const int* __restrict__ ecol,
                                              const u32* __restrict__ X16, float* Yf, u32* Y16,
                                              float* ACC, int nrows) {
  int w = blockIdx.x * 4 + __builtin_amdgcn_readfirstlane(threadIdx.x >> 6);
  int lane = threadIdx.x & 63;
  if (w >= nrows) return;
  int s = ptr[w], t = ptr[w + 1];
  float ax = 0.f, ay = 0.f;
  int e = s;
  for (; e + 8 <= t; e += 8) {
    int cc[8];
    float vv[8];
#pragma unroll
    for (int k = 0; k < 8; ++k) {
      if (UNIT) {
        cc[k] = ecol[e + k];
      } else {
        u32 q = ep[e + k];
        cc[k] = (int)(q & 0xffffu);
        vv[k] = bhi(q);
      }
    }
    u32 p[8];
#pragma unroll
    for (int k = 0; k < 8; ++k) p[k] = X16[(size_t)cc[k] * 64 + lane];
#pragma unroll
    for (int k = 0; k < 8; ++k) {
      if (UNIT) {
        ax += blo(p[k]);
        ay += bhi(p[k]);
      } else {
        ax += vv[k] * blo(p[k]);
        ay += vv[k] * bhi(p[k]);
      }
    }
  }
  for (; e + 4 <= t; e += 4) {
    int cc[4];
    float vv[4];
#pragma unroll
    for (int k = 0; k < 4; ++k) {
      if (UNIT) {
        cc[k] = ecol[e + k];
      } else {
        u32 q = ep[e + k];
        cc[k] = (int)(q & 0xffffu);
        vv[k] = bhi(q);
      }
    }
    u32 p[4];
#pragma unroll
    for (int k = 0; k < 4; ++k) p[k] = X16[(size_t)cc[k] * 64 + lane];
#pragma unroll
    for (int k = 0; k < 4; ++k) {
      if (UNIT) {
        ax += blo(p[k]);
        ay += bhi(p[k]);
      } else {
        ax += vv[k] * blo(p[k]);
        ay += vv[k] * bhi(p[k]);
      }
    }
  }
  for (; e < t; ++e) {
    int c;
    float v = 1.f;
    if (UNIT) {
      c = ecol[e];
    } else {
      u32 q = ep[e];
      c = (int)(q & 0xffffu);
      v = bhi(q);
    }
    u32 p = X16[(size_t)c * 64 + lane];
    ax += v * blo(p);
    ay += v * bhi(p);
  }
  size_t b64 = (size_t)w * 64 + lane;
  if (Yf) *(float2*)(Yf + 2 * b64) = make_float2(ax, ay);
  if (Y16) Y16[b64] = pack_bf16x2(ax, ay);
  if (ACC) {
    float ss = wave_sum64(ax * ax + ay * ay);
    float rs = rsqrtf(fmaxf(ss, 1e-12f));
    float2* a = (float2*)(ACC + 2 * b64);
    float2 o = *a;
    o.x += ax * rs;
    o.y += ay * rs;
    *a = o;
  }
}

// ---------------- channel attention softmax mix ----------------
template <bool SRC16, bool OUT16>
__global__ __launch_bounds__(256) void k_mix(const void* __restrict__ c0_,
                                             const void* __restrict__ c1_,
                                             const void* __restrict__ c2_,
                                             const float* __restrict__ sp,
                                             const float* __restrict__ attv, float* outf,
                                             u32* out16, int nrows) {
  int w = blockIdx.x * 4 + __builtin_amdgcn_readfirstlane(threadIdx.x >> 6);
  int lane = threadIdx.x & 63;
  if (w >= nrows) return;
  size_t b64 = (size_t)w * 64 + lane;
  float2 x0, x1, x2;
  if (SRC16) {
    u32 p0 = ((const u32*)c0_)[b64];
    u32 p1 = ((const u32*)c1_)[b64];
    u32 p2 = ((const u32*)c2_)[b64];
    x0 = make_float2(blo(p0), bhi(p0));
    x1 = make_float2(blo(p1), bhi(p1));
    x2 = make_float2(blo(p2), bhi(p2));
  } else {
    x0 = *(const float2*)((const float*)c0_ + 2 * b64);
    x1 = *(const float2*)((const float*)c1_ + 2 * b64);
    x2 = *(const float2*)((const float*)c2_ + 2 * b64);
  }
  float2 av = *(const float2*)(attv + lane * 2);
  float w0 = wave_sum64(x0.x * av.x + x0.y * av.y);
  float w1 = wave_sum64(x1.x * av.x + x1.y * av.y);
  float w2 = wave_sum64(x2.x * av.x + x2.y * av.y);
  float m = fmaxf(w0, fmaxf(w1, w2));
  float e0 = __expf(w0 - m), e1 = __expf(w1 - m), e2 = __expf(w2 - m);
  float inv = 1.f / (e0 + e1 + e2);
  float s0 = e0 * inv, s1 = e1 * inv, s2 = e2 * inv;
  float2 sv = *(const float2*)(sp + 2 * b64);
  float ox = s0 * x0.x + s1 * x1.x + s2 * x2.x + 0.5f * sv.x;
  float oy = s0 * x0.y + s1 * x1.y + s2 * x2.y + 0.5f * sv.y;
  if (OUT16)
    out16[b64] = pack_bf16x2(ox, oy);
  else
    *(float2*)(outf + 2 * b64) = make_float2(ox, oy);
}

// ---------------- launch ----------------
extern "C" void kernel_launch(void* const* d_in, const int* in_sizes, int n_in, void* d_out,
                              int out_size, void* d_ws, size_t ws_size, hipStream_t stream) {
  const float* u_emb = (const float*)d_in[0];
  const float* i_emb = (const float*)d_in[1];
  const float* gW = (const float*)d_in[2];
  const float* gB = (const float*)d_in[3];
  const float* att = (const float*)d_in[4];
  const float* attm = (const float*)d_in[5];
  Graphs g;
  g.row[0] = (const int*)d_in[6];
  g.col[0] = (const int*)d_in[7];
  g.val[0] = (const float*)d_in[8];
  g.row[1] = (const int*)d_in[9];
  g.col[1] = (const int*)d_in[10];
  g.val[1] = (const float*)d_in[11];
  g.row[2] = (const int*)d_in[12];
  g.col[2] = (const int*)d_in[13];
  g.val[2] = (const float*)d_in[14];
  g.row[3] = (const int*)d_in[15];  // R: user rows
  g.col[3] = (const int*)d_in[16];
  g.val[3] = (const float*)d_in[17];
  g.row[4] = (const int*)d_in[16];  // R^T: item rows
  g.col[4] = (const int*)d_in[15];
  g.val[4] = (const float*)d_in[17];

  const size_t U = (size_t)NU * DIMN, U64 = (size_t)NU * 64, I64 = (size_t)NI * 64;
  const size_t ETOT = 3 * (size_t)EH + 2 * (size_t)ER;  // 3.8M
  float* f = (float*)d_ws;
  float* G0 = f;
  float* G1 = G0 + U;
  float* G2 = G1 + U;
  float* S = G2 + U;
  u32* G016 = (u32*)(S + U);
  u32* G116 = G016 + U64;
  u32* G216 = G116 + U64;
  u32* C1016 = G216 + U64;
  u32* C1116 = C1016 + U64;
  u32* C1216 = C1116 + U64;
  u32* MIX16 = C1216 + U64;
  u32* I116 = MIX16 + U64;
  u32* IE16 = I116 + I64;
  float* attv = (float*)(IE16 + I64);
  int* ptrA = (int*)(attv + DIMN);  // 225005 (+pad)
  int* bcnt = ptrA + 225008;        // 980
  int* bbase = bcnt + 980;          // 981
  int* bcur = bbase + 984;          // 980
  uintptr_t ek_addr = ((uintptr_t)(bcur + 980) + 15u) & ~(uintptr_t)15;
  u64* ebkt = (u64*)ek_addr;             // 3.8M u64 (row|payload), bucketed
  u32* epay = (u32*)(ebkt + ETOT);       // 3.8M u32 final CSR payloads
  u32* epH = epay;                       // H payloads at [z*EH]
  int* ecR = (int*)(epay + 3 * (size_t)EH);  // R cols at [0], RT at [ER]
  float* out_u = (float*)d_out;
  float* out_i = out_u + U;

  const int CHB = (ER + CHUNK - 1) / CHUNK;  // 489

  // ---- bucketed CSR build ----
  hipMemsetAsync(bcnt, 0, 980 * sizeof(int), stream);
  hipLaunchKernelGGL(k_bcount, dim3(CHB, 5), dim3(256), 0, stream, g, bcnt);
  hipLaunchKernelGGL(k_bscan, dim3(1), dim3(256), 0, stream, bcnt, bbase, bcur, ptrA);
  hipLaunchKernelGGL(k_bscat, dim3(CHB, 5), dim3(256), 0, stream, g, bcur, ebkt);
  hipLaunchKernelGGL(k_fine, dim3(NBK, 5), dim3(256), 0, stream, ebkt, bbase, epay, ptrA);

  // ---- dense prep ----
  hipLaunchKernelGGL(k_attvec, dim3(1), dim3(128), 0, stream, attm, att, attv);
  hipLaunchKernelGGL(k_gate, dim3(782, 4), dim3(256), 0, stream, u_emb, gW, gB, G0, G1, G2, S,
                     out_u, G016, G116, G216, NU);
  hipLaunchKernelGGL(k_copy_ie, dim3((NI * 64 + 255) / 256), dim3(256), 0, stream, i_emb, out_i,
                     IE16, NI * 64);

  const int poffs[5] = {0, NU + 1, 2 * NU + 2, 3 * NU + 3, 4 * NU + 4};
  const int GRID_U = (NU + 3) / 4;  // 4 rows (waves) per block
  const int GRID_I = (NI + 3) / 4;

  // ---- layer 1 ----
  hipLaunchKernelGGL((k_mix<false, true>), dim3(GRID_U), dim3(256), 0, stream, G0, G1, G2, S, attv,
                     (float*)nullptr, MIX16, NU);
  // new_item = R^T @ mixed ; I116 + out_i += l2norm
  hipLaunchKernelGGL((k_spmm<true>), dim3(GRID_I), dim3(256), 0, stream, ptrA + poffs[4],
                     (const u32*)nullptr, ecR + ER, MIX16, (float*)nullptr, I116, out_i, NI);
  // cur_s = R @ i_emb ; S fp32 + out_u += l2norm
  hipLaunchKernelGGL((k_spmm<true>), dim3(GRID_U), dim3(256), 0, stream, ptrA + poffs[3],
                     (const u32*)nullptr, ecR, IE16, S, (u32*)nullptr, out_u, NU);
  // channel spmms: gather Gk16 -> C1k16, fused norm-acc into Gk fp32 (distinct buffers)
  hipLaunchKernelGGL((k_spmm<false>), dim3(GRID_U), dim3(256), 0, stream, ptrA + poffs[0], epH,
                     (const int*)nullptr, G016, (float*)nullptr, C1016, G0, NU);
  hipLaunchKernelGGL((k_spmm<false>), dim3(GRID_U), dim3(256), 0, stream, ptrA + poffs[1],
                     epH + EH, (const int*)nullptr, G116, (float*)nullptr, C1116, G1, NU);
  hipLaunchKernelGGL((k_spmm<false>), dim3(GRID_U), dim3(256), 0, stream, ptrA + poffs[2],
                     epH + 2 * (size_t)EH, (const int*)nullptr, G216, (float*)nullptr, C1216, G2,
                     NU);

  // ---- layer 2 ----
  hipLaunchKernelGGL((k_mix<true, true>), dim3(GRID_U), dim3(256), 0, stream, C1016, C1116, C1216,
                     S, attv, (float*)nullptr, MIX16, NU);
  hipLaunchKernelGGL((k_spmm<true>), dim3(GRID_I), dim3(256), 0, stream, ptrA + poffs[4],
                     (const u32*)nullptr, ecR + ER, MIX16, (float*)nullptr, (u32*)nullptr, out_i,
                     NI);
  hipLaunchKernelGGL((k_spmm<true>), dim3(GRID_U), dim3(256), 0, stream, ptrA + poffs[3],
                     (const u32*)nullptr, ecR, I116, (float*)nullptr, (u32*)nullptr, out_u, NU);
  hipLaunchKernelGGL((k_spmm<false>), dim3(GRID_U), dim3(256), 0, stream, ptrA + poffs[0], epH,
                     (const int*)nullptr, C1016, (float*)nullptr, (u32*)nullptr, G0, NU);
  hipLaunchKernelGGL((k_spmm<false>), dim3(GRID_U), dim3(256), 0, stream, ptrA + poffs[1],
                     epH + EH, (const int*)nullptr, C1116, (float*)nullptr, (u32*)nullptr, G1, NU);
  hipLaunchKernelGGL((k_spmm<false>), dim3(GRID_U), dim3(256), 0, stream, ptrA + poffs[2],
                     epH + 2 * (size_t)EH, (const int*)nullptr, C1216, (float*)nullptr,
                     (u32*)nullptr, G2, NU);

  // ---- final: out_u = chan_att(fc) + 0.5*sum(all_s) ----
  hipLaunchKernelGGL((k_mix<false, false>), dim3(GRID_U), dim3(256), 0, stream, G0, G1, G2, out_u,
                     attv, out_u, (u32*)nullptr, NU);
}